// Round 16
// baseline (214.855 us; speedup 1.0000x reference)
//
#include <hip/hip_runtime.h>
#include <hip/hip_bf16.h>

typedef __attribute__((ext_vector_type(8))) short short8;
typedef __attribute__((ext_vector_type(4))) float f32x4;
typedef __attribute__((ext_vector_type(4))) unsigned int u32x4;

#define MFMA16(A, B, C) __builtin_amdgcn_mfma_f32_16x16x32_bf16(A, B, C, 0, 0, 0)

__device__ __forceinline__ unsigned int pkbf(float lo, float hi) {
  unsigned int ul = (unsigned int)__bfloat16_as_ushort(__float2bfloat16(lo));
  unsigned int uh = (unsigned int)__bfloat16_as_ushort(__float2bfloat16(hi));
  return ul | (uh << 16);
}

union S8U { short8 s; u32x4 u; };
__device__ __forceinline__ short8 mk8(unsigned int a, unsigned int b,
                                      unsigned int c, unsigned int d) {
  S8U t; u32x4 v = {a, b, c, d}; t.u = v; return t.s;
}

constexpr float SU = 0.24430125595146f;   // (1/sqrt2)*sqrt(3/8)/sqrt(pi)
constexpr float SW = 0.34549414947134f;   // (1/sqrt2)*sqrt(3/4)/sqrt(pi)

// MFMA 16x16x32 bf16 layouts (HW-verified, rounds 2-3):
//   A: lane l holds A[row=l&15][k=8*(l>>4)+e];  B: lane l holds B[k=8*(l>>4)+e][col=l&15]
//   C/D: lane l reg v holds D[row=4*(l>>4)+v][col=l&15]

// ============ Kernel A: partial TP — component-split for 3 waves/SIMD ============
// grid 2048: bid = (((nq*2 + fh)*2 + ph)*2 + cs); 256 threads (4 waves).
// REGISTER WINDOW (r5/9/11/12): total arch+acc <= 256 -> 2 w/SIMD; <= 170 -> 3.
// r10 sat at ~190 (48 of it = accT[2][6]). cs-split: each block computes only
// out_cs's 3 TP components -> accT[2][3] frees 24 regs -> total ~166 <= 170 ->
// 3 blocks/CU from the CHEAP side (no forced cap, no spill). MFMA work x2
// (util 6%->12%, affordable); rbf/uv twin readers are consecutive bids (L2).
__global__ __launch_bounds__(256) void tfield_partial(
    const float* __restrict__ rbf,  const float* __restrict__ uv,
    const float* __restrict__ inp1, const float* __restrict__ inp2,
    const float* __restrict__ W1,   const float* __restrict__ b1,
    const float* __restrict__ W2,   const float* __restrict__ b2,
    float* __restrict__ ws)
{
  __shared__ __align__(16) unsigned char pool[27008];
  unsigned int* wfrag = (unsigned int*)pool;             // 12 frags x 64 x 16B
  unsigned int* hbuf  = (unsigned int*)(pool + 12288);   // 4 waves x 16 rows x 128B
  float* ibuf  = (float*)(pool + 20480);                 // 4 waves x 2 slots x 192 f32
  float* biasL = (float*)(pool + 26624);                 // 64 b1 + 32 b2-half
  float* accL  = (float*)pool;                           // epilogue reuse (1536 f32)

  const int tid = threadIdx.x;
  const int l   = tid & 63;
  const int w   = tid >> 6;     // wave 0..3
  const int g   = l >> 4;
  const int qh  = l & 15;
  const int bid = blockIdx.x;
  const int nq  = bid >> 3;
  const int fh  = (bid >> 2) & 1;
  const int ph  = (bid >> 1) & 1;
  const int cs  = bid & 1;      // 0: out1 components, 1: out2 components
  const int n   = nq >> 4;
  const int q0  = (nq & 15) << 4;

  // ---- stage 12 W fragments (W1: 0..7, W2-half: 8..11) + biases ----
  #pragma unroll
  for (int k = 0; k < 3; ++k) {
    const int slot = tid + (k << 8);
    const int fi = slot >> 6;
    const int ll = slot & 63;
    const int gg = ll >> 4;
    const int qq = ll & 15;
    const float* src;
    if (fi < 8) {
      src = W1 + ((fi >> 1) * 16 + qq) * 64 + (fi & 1) * 32 + gg * 8;
    } else {
      const int fj = fi - 8;
      src = W2 + (((fh << 1) + (fj >> 1)) * 16 + qq) * 64 + (fj & 1) * 32 + gg * 8;
    }
    f32x4 x0 = *(const f32x4*)src;
    f32x4 x1 = *(const f32x4*)(src + 4);
    u32x4 vv = {pkbf(x0[0], x0[1]), pkbf(x0[2], x0[3]), pkbf(x1[0], x1[1]), pkbf(x1[2], x1[3])};
    *(u32x4*)(wfrag + ((fi << 6) + ll) * 4) = vv;
  }
  if (tid < 96) biasL[tid] = (tid < 64) ? b1[tid] : b2[(fh << 5) + tid - 64];
  __syncthreads();

  const float* bL1 = biasL;        // b1[f], f = 16mt+4g+v
  const float* bL2 = biasL + 64;   // b2[fh*32 + 16mt2l+4g+v]

  f32x4 accT[2][3];
  #pragma unroll
  for (int a = 0; a < 2; ++a)
    #pragma unroll
    for (int j = 0; j < 3; ++j) accT[a][j] = (f32x4){0.f, 0.f, 0.f, 0.f};

  const size_t nbase = (size_t)n * 256;
  const int pbase = (ph << 7) + w;   // wave w: p = pbase + 4*s, s in [0,32)

  const int sl = (l < 24) ? l : l - 24;
  const float* isrcb = (l < 24) ? inp1 : inp2;
  const int ioff = (sl >> 3) * 64 + (fh << 5) + ((sl & 7) << 2);

  unsigned int* hrow = hbuf + (w << 9) + (qh << 5);
  float* iw = ibuf + w * 384;          // 2 slots x 192 floats
  const int swz = qh & 7;

  // ---- prologue: L1(0) + stage inp(0)/h(0); prefetch step-1 data ----
  f32x4 rn0, rn1, rn2, rn3;
  { const float* rr = rbf + ((nbase + pbase) * 256 + q0 + qh) * 64 + (g << 3);
    rn0 = *(const f32x4*)rr;        rn1 = *(const f32x4*)(rr + 4);
    rn2 = *(const f32x4*)(rr + 32); rn3 = *(const f32x4*)(rr + 36); }
  f32x4 stage_v = {0.f, 0.f, 0.f, 0.f};
  if (l < 48) stage_v = *(const f32x4*)(isrcb + (nbase + pbase) * 192 + ioff);
  float uc0, uc1, uc2, un0, un1, un2;
  { const float* u = uv + ((nbase + pbase) * 256 + q0 + qh) * 3;
    uc0 = u[0]; uc1 = u[1]; uc2 = u[2]; }

  short8 rf0 = mk8(pkbf(rn0[0], rn0[1]), pkbf(rn0[2], rn0[3]), pkbf(rn1[0], rn1[1]), pkbf(rn1[2], rn1[3]));
  short8 rf1 = mk8(pkbf(rn2[0], rn2[1]), pkbf(rn2[2], rn2[3]), pkbf(rn3[0], rn3[1]), pkbf(rn3[2], rn3[3]));
  f32x4 h4[4];
  #pragma unroll
  for (int mt = 0; mt < 4; ++mt) {
    f32x4 c = *(const f32x4*)(bL1 + (mt << 4) + (g << 2));
    short8 a0 = *(const short8*)(wfrag + (((mt << 1) + 0) * 64 + l) * 4);
    short8 a1 = *(const short8*)(wfrag + (((mt << 1) + 1) * 64 + l) * 4);
    c = MFMA16(a0, rf0, c);
    c = MFMA16(a1, rf1, c);
    h4[mt] = c;
  }
  if (l < 48) *(f32x4*)(iw + (l << 2)) = stage_v;          // slot0 = inp(0)
  #pragma unroll
  for (int mt = 0; mt < 4; ++mt) {
    const float e0 = fmaxf(h4[mt][0], 0.f);
    const float e1 = fmaxf(h4[mt][1], 0.f);
    const float e2 = fmaxf(h4[mt][2], 0.f);
    const float e3 = fmaxf(h4[mt][3], 0.f);
    const int base = ((((mt << 1) + (g >> 1)) ^ swz) << 2) + ((g & 1) << 1);
    hrow[base]     = pkbf(e0, e1);
    hrow[base + 1] = pkbf(e2, e3);
  }
  short8 hb0 = *(const short8*)(hrow + (((0 + g) ^ swz) << 2));
  short8 hb1 = *(const short8*)(hrow + (((4 + g) ^ swz) << 2));
  // prefetch step-1 inputs
  { const float* rr = rbf + ((nbase + pbase + 4) * 256 + q0 + qh) * 64 + (g << 3);
    rn0 = *(const f32x4*)rr;        rn1 = *(const f32x4*)(rr + 4);
    rn2 = *(const f32x4*)(rr + 32); rn3 = *(const f32x4*)(rr + 36); }
  if (l < 48) stage_v = *(const f32x4*)(isrcb + (nbase + pbase + 4) * 192 + ioff);
  { const float* u = uv + ((nbase + pbase + 4) * 256 + q0 + qh) * 3;
    un0 = u[0]; un1 = u[1]; un2 = u[2]; }

  for (int s = 0; s < 32; ++s) {
    const int s2 = (s + 2 < 32) ? s + 2 : 31;    // clamped two-ahead prefetch index

    // A: pack rbf(s+1) and start L1 MFMA for step s+1
    rf0 = mk8(pkbf(rn0[0], rn0[1]), pkbf(rn0[2], rn0[3]), pkbf(rn1[0], rn1[1]), pkbf(rn1[2], rn1[3]));
    rf1 = mk8(pkbf(rn2[0], rn2[1]), pkbf(rn2[2], rn2[3]), pkbf(rn3[0], rn3[1]), pkbf(rn3[2], rn3[3]));
    #pragma unroll
    for (int mt = 0; mt < 4; ++mt) {
      f32x4 c = *(const f32x4*)(bL1 + (mt << 4) + (g << 2));
      short8 a0 = *(const short8*)(wfrag + (((mt << 1) + 0) * 64 + l) * 4);
      short8 a1 = *(const short8*)(wfrag + (((mt << 1) + 1) * 64 + l) * 4);
      c = MFMA16(a0, rf0, c);
      c = MFMA16(a1, rf1, c);
      h4[mt] = c;
    }
    // issue rbf(s+2) loads
    { const float* rr = rbf + ((nbase + pbase + (s2 << 2)) * 256 + q0 + qh) * 64 + (g << 3);
      rn0 = *(const f32x4*)rr;        rn1 = *(const f32x4*)(rr + 4);
      rn2 = *(const f32x4*)(rr + 32); rn3 = *(const f32x4*)(rr + 36); }

    // C: L2 MFMA for step s
    f32x4 cc0, cc1;
    {
      f32x4 c = *(const f32x4*)(bL2 + (g << 2));
      short8 wa0 = *(const short8*)(wfrag + ((8 + 0) * 64 + l) * 4);
      short8 wa1 = *(const short8*)(wfrag + ((8 + 1) * 64 + l) * 4);
      c = MFMA16(wa0, hb0, c);
      c = MFMA16(wa1, hb1, c);
      cc0 = c;
      c = *(const f32x4*)(bL2 + 16 + (g << 2));
      wa0 = *(const short8*)(wfrag + ((8 + 2) * 64 + l) * 4);
      wa1 = *(const short8*)(wfrag + ((8 + 3) * 64 + l) * 4);
      c = MFMA16(wa0, hb0, c);
      c = MFMA16(wa1, hb1, c);
      cc1 = c;
    }

    // factors for step s; roll uv prefetch
    const float su  = SU * uc0;
    const float sv  = SU * uc1;
    const float swc = SW * uc2;
    uc0 = un0; uc1 = un1; uc2 = un2;
    { const float* u = uv + ((nbase + pbase + (s2 << 2)) * 256 + q0 + qh) * 3;
      un0 = u[0]; un1 = u[1]; un2 = u[2]; }

    // D: TP(s) — only this block's 3 components (cs-split)
    const float* ib = iw + ((s & 1) * 192) + (g << 2);
    #pragma unroll
    for (int mt2l = 0; mt2l < 2; ++mt2l) {
      const f32x4 A0 = *(const f32x4*)(ib + (mt2l << 4));
      const f32x4 A1 = *(const f32x4*)(ib + (mt2l << 4) + 32);
      const f32x4 A2 = *(const f32x4*)(ib + (mt2l << 4) + 64);
      const f32x4 B0 = *(const f32x4*)(ib + (mt2l << 4) + 96);
      const f32x4 B1 = *(const f32x4*)(ib + (mt2l << 4) + 128);
      const f32x4 B2 = *(const f32x4*)(ib + (mt2l << 4) + 160);
      const f32x4 cc = mt2l ? cc1 : cc0;

      if (cs == 0) {   // out1: g10, g11, g12
        const f32x4 t1 = su * A1, t2 = sv * B1;
        const f32x4 g10 = (t1 + t2) - swc * A0;
        const f32x4 g11 = su * (A0 + A2) - sv * (B0 - B2);
        const f32x4 g12 = (t1 - t2) + swc * A2;
        accT[mt2l][0] += cc * g10;
        accT[mt2l][1] += cc * g11;
        accT[mt2l][2] += cc * g12;
      } else {         // out2: g20, g21, g22
        const f32x4 t3 = su * B1, t4 = sv * A1;
        const f32x4 g20 = (t3 - t4) - swc * B0;
        const f32x4 g21 = sv * (A0 - A2) + su * (B0 + B2);
        const f32x4 g22 = (t3 + t4) + swc * B2;
        accT[mt2l][0] += cc * g20;
        accT[mt2l][1] += cc * g21;
        accT[mt2l][2] += cc * g22;
      }
    }

    // E: roll inp staging
    if (l < 48) *(f32x4*)(iw + (((s + 1) & 1) * 192) + (l << 2)) = stage_v;
    if (l < 48) stage_v = *(const f32x4*)(isrcb + (nbase + pbase + (s2 << 2)) * 192 + ioff);

    // E2: relu/pack h(s+1) -> LDS transpose; read hb(s+1)
    #pragma unroll
    for (int mt = 0; mt < 4; ++mt) {
      const float e0 = fmaxf(h4[mt][0], 0.f);
      const float e1 = fmaxf(h4[mt][1], 0.f);
      const float e2 = fmaxf(h4[mt][2], 0.f);
      const float e3 = fmaxf(h4[mt][3], 0.f);
      const int base = ((((mt << 1) + (g >> 1)) ^ swz) << 2) + ((g & 1) << 1);
      hrow[base]     = pkbf(e0, e1);
      hrow[base + 1] = pkbf(e2, e3);
    }
    hb0 = *(const short8*)(hrow + (((0 + g) ^ swz) << 2));
    hb1 = *(const short8*)(hrow + (((4 + g) ^ swz) << 2));
  }

  // ---- cross-wave reduce into accL [16 qh][32 fl][3], dump to ws ----
  __syncthreads();
  for (int i = tid; i < 1536; i += 256) accL[i] = 0.f;
  __syncthreads();
  for (int t = 0; t < 4; ++t) {
    if (w == t) {
      #pragma unroll
      for (int mt2l = 0; mt2l < 2; ++mt2l)
        #pragma unroll
        for (int v = 0; v < 4; ++v) {
          float* dst = accL + (((qh << 5) + (mt2l << 4) + (g << 2) + v) * 3);
          #pragma unroll
          for (int j = 0; j < 3; ++j) dst[j] += accT[mt2l][j][v];
        }
    }
    __syncthreads();
  }
  float* wp = ws + (size_t)bid * 1536;
  for (int i = tid; i < 1536; i += 256) wp[i] = accL[i];
}

// ============ Kernel B: combine 8 partials + normalize + project + gate ============
__global__ __launch_bounds__(512) void tfield_finish(
    const float* __restrict__ ws, const float* __restrict__ Wsi,
    const float* __restrict__ biasb, float* __restrict__ out)
{
  __shared__ __align__(16) float accL[6144];   // [16 qh][64 f][6]
  __shared__ __align__(16) float wsiT[4096];   // [64 f][64 g]

  const int tid = threadIdx.x;
  const int l   = tid & 63;
  const int w   = tid >> 6;
  const int nq  = blockIdx.x;
  const int n   = nq >> 4;
  const int q0  = (nq & 15) << 4;

  // partials: bid = nq*8 + fh*4 + ph*2 + cs; each 1536 f32 [16qh][32fl][3j]
  const float* base = ws + (size_t)nq * 8 * 1536;
  #pragma unroll
  for (int fh = 0; fh < 2; ++fh)
    #pragma unroll
    for (int cs = 0; cs < 2; ++cs) {
      const float* p0 = base + (fh * 4 + 0 * 2 + cs) * 1536;
      const float* p1 = base + (fh * 4 + 1 * 2 + cs) * 1536;
      for (int i = tid; i < 1536; i += 512) {
        const int qhh = i / 96;
        const int rem = i - qhh * 96;
        const int fl  = rem / 3;
        const int j   = rem - fl * 3;
        accL[((qhh << 6) + (fh << 5) + fl) * 6 + cs * 3 + j] = p0[i] + p1[i];
      }
    }
  #pragma unroll
  for (int k = 0; k < 8; ++k) {
    const int f = (w << 3) + k;
    wsiT[(f << 6) + l] = Wsi[(l << 6) + f];
  }
  __syncthreads();

  #pragma unroll
  for (int rep = 0; rep < 2; ++rep) {
    const int qq = w + (rep << 3);
    float* xp = accL + ((qq << 6) + l) * 6;
    const float x0 = xp[0], x1 = xp[1], x2 = xp[2], x3 = xp[3], x4 = xp[4], x5 = xp[5];
    const float nrm = sqrtf(x0*x0 + x1*x1 + x2*x2 + x3*x3 + x4*x4 + x5*x5);
    const float sc = 1.f / (nrm + 1e-9f);
    xp[0] = x0 * sc; xp[1] = x1 * sc; xp[2] = x2 * sc;
    xp[3] = x3 * sc; xp[4] = x4 * sc; xp[5] = x5 * sc;
  }
  __syncthreads();

  const float bb = biasb[0];
  #pragma unroll
  for (int rep = 0; rep < 2; ++rep) {
    const int qq = w + (rep << 3);
    const float* arow = accL + (qq << 6) * 6;
    float pj0 = 0, pj1 = 0, pj2 = 0, pj3 = 0, pj4 = 0, pj5 = 0;
    for (int f = 0; f < 64; ++f) {
      const float wv = wsiT[(f << 6) + l];
      const float* ap = arow + f * 6;
      pj0 += ap[0] * wv; pj1 += ap[1] * wv; pj2 += ap[2] * wv;
      pj3 += ap[3] * wv; pj4 += ap[4] * wv; pj5 += ap[5] * wv;
    }
    const float s2 = pj0*pj0 + pj1*pj1 + pj2*pj2 + pj3*pj3 + pj4*pj4 + pj5*pj5;
    const float nl = fmaxf(sqrtf(s2) + bb, 0.f);
    const int q = q0 + qq;
    float* o1 = out + (size_t)((n * 256 + q) * 3) * 64 + l;   // out1[n,q,c,g]
    float* o2 = o1 + 786432;                                   // out2
    o1[0]   = pj0 * nl;
    o1[64]  = pj1 * nl;
    o1[128] = pj2 * nl;
    o2[0]   = pj3 * nl;
    o2[64]  = pj4 * nl;
    o2[128] = pj5 * nl;
  }
}

// ============ Fallback: round-4 monolithic kernel (used if ws too small) ============
__global__ __launch_bounds__(512) void tfield_kernel(
    const float* __restrict__ rbf,  const float* __restrict__ uv,
    const float* __restrict__ inp1, const float* __restrict__ inp2,
    const float* __restrict__ W1,   const float* __restrict__ b1,
    const float* __restrict__ W2,   const float* __restrict__ b2,
    const float* __restrict__ Wsi,  const float* __restrict__ biasb,
    float* __restrict__ out)
{
  __shared__ __align__(16) unsigned char pool[40960];
  unsigned int* wfrag = (unsigned int*)pool;
  unsigned int* hbuf  = (unsigned int*)(pool + 16384);
  float* accL = (float*)pool;
  float* wsiT = (float*)(pool + 24576);

  const int tid = threadIdx.x;
  const int l   = tid & 63;
  const int w   = tid >> 6;
  const int g   = l >> 4;
  const int qh  = l & 15;
  const int n   = blockIdx.x >> 4;
  const int q0  = (blockIdx.x & 15) << 4;

  {
    const int row = ((w >> 1) << 4) + qh;
    const int kb  = ((w & 1) << 5) + (g << 3);
    const float* s1 = W1 + row * 64 + kb;
    f32x4 x0 = *(const f32x4*)s1;
    f32x4 x1 = *(const f32x4*)(s1 + 4);
    u32x4 v1 = {pkbf(x0[0], x0[1]), pkbf(x0[2], x0[3]), pkbf(x1[0], x1[1]), pkbf(x1[2], x1[3])};
    *(u32x4*)(wfrag + ((w << 6) + l) * 4) = v1;
    const float* s2 = W2 + row * 64 + kb;
    x0 = *(const f32x4*)s2;
    x1 = *(const f32x4*)(s2 + 4);
    u32x4 v2 = {pkbf(x0[0], x0[1]), pkbf(x0[2], x0[3]), pkbf(x1[0], x1[1]), pkbf(x1[2], x1[3])};
    *(u32x4*)(wfrag + (((8 + w) << 6) + l) * 4) = v2;
  }
  __syncthreads();

  float accT[4][4][6];
  #pragma unroll
  for (int a = 0; a < 4; ++a)
    #pragma unroll
    for (int b = 0; b < 4; ++b)
      #pragma unroll
      for (int j = 0; j < 6; ++j) accT[a][b][j] = 0.f;

  const size_t nbase = (size_t)n * 256;
  const float* rr0 = rbf + ((nbase + w) * 256 + q0 + qh) * 64 + (g << 3);
  f32x4 nx0 = *(const f32x4*)(rr0);
  f32x4 nx1 = *(const f32x4*)(rr0 + 4);
  f32x4 nx2 = *(const f32x4*)(rr0 + 32);
  f32x4 nx3 = *(const f32x4*)(rr0 + 36);

  unsigned int* hrow = hbuf + ((w << 4) + qh) * 32;
  const int swz = qh & 7;

  for (int s = 0; s < 32; ++s) {
    const int p = (s << 3) + w;
    f32x4 r0 = nx0, r1 = nx1, r2 = nx2, r3 = nx3;
    {
      const int pn = (s < 31) ? p + 8 : p;
      const float* rr = rbf + ((nbase + pn) * 256 + q0 + qh) * 64 + (g << 3);
      nx0 = *(const f32x4*)(rr);
      nx1 = *(const f32x4*)(rr + 4);
      nx2 = *(const f32x4*)(rr + 32);
      nx3 = *(const f32x4*)(rr + 36);
    }
    const float* uvp = uv + ((nbase + p) * 256 + q0 + qh) * 3;
    const float su = SU * uvp[0];
    const float sv = SU * uvp[1];
    const float swc = SW * uvp[2];

    const short8 rf0 = mk8(pkbf(r0[0], r0[1]), pkbf(r0[2], r0[3]), pkbf(r1[0], r1[1]), pkbf(r1[2], r1[3]));
    const short8 rf1 = mk8(pkbf(r2[0], r2[1]), pkbf(r2[2], r2[3]), pkbf(r3[0], r3[1]), pkbf(r3[2], r3[3]));

    f32x4 h4[4];
    #pragma unroll
    for (int mt = 0; mt < 4; ++mt) {
      f32x4 c = *(const f32x4*)(b1 + (mt << 4) + (g << 2));
      short8 a0 = *(const short8*)(wfrag + (((mt << 1) + 0) * 64 + l) * 4);
      short8 a1 = *(const short8*)(wfrag + (((mt << 1) + 1) * 64 + l) * 4);
      c = MFMA16(a0, rf0, c);
      c = MFMA16(a1, rf1, c);
      h4[mt] = c;
    }
    #pragma unroll
    for (int mt = 0; mt < 4; ++mt) {
      const float e0 = fmaxf(h4[mt][0], 0.f);
      const float e1 = fmaxf(h4[mt][1], 0.f);
      const float e2 = fmaxf(h4[mt][2], 0.f);
      const float e3 = fmaxf(h4[mt][3], 0.f);
      const int base = ((((mt << 1) + (g >> 1)) ^ swz) << 2) + ((g & 1) << 1);
      hrow[base]     = pkbf(e0, e1);
      hrow[base + 1] = pkbf(e2, e3);
    }
    const short8 hb0 = *(const short8*)(hrow + (((0 + g) ^ swz) << 2));
    const short8 hb1 = *(const short8*)(hrow + (((4 + g) ^ swz) << 2));

    const float* i1p = inp1 + (nbase + p) * 192 + (g << 2);
    const float* i2p = inp2 + (nbase + p) * 192 + (g << 2);

    #pragma unroll
    for (int mt2 = 0; mt2 < 4; ++mt2) {
      f32x4 c = *(const f32x4*)(b2 + (mt2 << 4) + (g << 2));
      short8 wa0 = *(const short8*)(wfrag + ((8 + (mt2 << 1) + 0) * 64 + l) * 4);
      short8 wa1 = *(const short8*)(wfrag + ((8 + (mt2 << 1) + 1) * 64 + l) * 4);
      c = MFMA16(wa0, hb0, c);
      c = MFMA16(wa1, hb1, c);

      const int fo = mt2 << 4;
      const f32x4 A0 = *(const f32x4*)(i1p + fo);
      const f32x4 A1 = *(const f32x4*)(i1p + fo + 64);
      const f32x4 A2 = *(const f32x4*)(i1p + fo + 128);
      const f32x4 B0 = *(const f32x4*)(i2p + fo);
      const f32x4 B1 = *(const f32x4*)(i2p + fo + 64);
      const f32x4 B2 = *(const f32x4*)(i2p + fo + 128);
      const f32x4 a02p = A0 + A2, a02m = A0 - A2;
      const f32x4 b02p = B0 + B2, b02m = B0 - B2;

      #pragma unroll
      for (int v = 0; v < 4; ++v) {
        const float R = c[v];
        const float pua1 = su * A1[v], pvb1 = sv * B1[v];
        const float pub1 = su * B1[v], pva1 = sv * A1[v];
        const float g10 = pua1 - swc * A0[v] + pvb1;
        const float g11 = su * a02p[v] - sv * b02m[v];
        const float g12 = swc * A2[v] + pua1 - pvb1;
        const float g20 = pub1 - swc * B0[v] - pva1;
        const float g21 = sv * a02m[v] + su * b02p[v];
        const float g22 = swc * B2[v] + pub1 + pva1;
        accT[mt2][v][0] += R * g10;
        accT[mt2][v][1] += R * g11;
        accT[mt2][v][2] += R * g12;
        accT[mt2][v][3] += R * g20;
        accT[mt2][v][4] += R * g21;
        accT[mt2][v][5] += R * g22;
      }
    }
  }

  __syncthreads();
  for (int i = tid; i < 16 * 64 * 6; i += 512) accL[i] = 0.f;
  #pragma unroll
  for (int k = 0; k < 8; ++k) {
    const int f = (w << 3) + k;
    wsiT[(f << 6) + l] = Wsi[(l << 6) + f];
  }
  __syncthreads();

  for (int t = 0; t < 8; ++t) {
    if (w == t) {
      #pragma unroll
      for (int mt2 = 0; mt2 < 4; ++mt2)
        #pragma unroll
        for (int v = 0; v < 4; ++v) {
          float* dst = accL + (((qh << 6) + (mt2 << 4) + (g << 2) + v) * 6);
          #pragma unroll
          for (int j = 0; j < 6; ++j) dst[j] += accT[mt2][v][j];
        }
    }
    __syncthreads();
  }

  #pragma unroll
  for (int rep = 0; rep < 2; ++rep) {
    const int qq = w + (rep << 3);
    float* xp = accL + ((qq << 6) + l) * 6;
    const float x0 = xp[0], x1 = xp[1], x2 = xp[2], x3 = xp[3], x4 = xp[4], x5 = xp[5];
    const float nrm = sqrtf(x0*x0 + x1*x1 + x2*x2 + x3*x3 + x4*x4 + x5*x5);
    const float sc = 1.f / (nrm + 1e-9f);
    xp[0] = x0 * sc; xp[1] = x1 * sc; xp[2] = x2 * sc;
    xp[3] = x3 * sc; xp[4] = x4 * sc; xp[5] = x5 * sc;
  }
  __syncthreads();

  const float bb = biasb[0];
  #pragma unroll
  for (int rep = 0; rep < 2; ++rep) {
    const int qq = w + (rep << 3);
    const float* arow = accL + (qq << 6) * 6;
    float pj0 = 0, pj1 = 0, pj2 = 0, pj3 = 0, pj4 = 0, pj5 = 0;
    for (int f = 0; f < 64; ++f) {
      const float wv = wsiT[(f << 6) + l];
      const float* ap = arow + f * 6;
      pj0 += ap[0] * wv; pj1 += ap[1] * wv; pj2 += ap[2] * wv;
      pj3 += ap[3] * wv; pj4 += ap[4] * wv; pj5 += ap[5] * wv;
    }
    const float s2 = pj0*pj0 + pj1*pj1 + pj2*pj2 + pj3*pj3 + pj4*pj4 + pj5*pj5;
    const float nl = fmaxf(sqrtf(s2) + bb, 0.f);
    const int q = q0 + qq;
    float* o1 = out + (size_t)((n * 256 + q) * 3) * 64 + l;
    float* o2 = o1 + 786432;
    o1[0]   = pj0 * nl;
    o1[64]  = pj1 * nl;
    o1[128] = pj2 * nl;
    o2[0]   = pj3 * nl;
    o2[64]  = pj4 * nl;
    o2[128] = pj5 * nl;
  }
}

extern "C" void kernel_launch(void* const* d_in, const int* in_sizes, int n_in,
                              void* d_out, int out_size, void* d_ws, size_t ws_size,
                              hipStream_t stream) {
  (void)in_sizes; (void)n_in; (void)out_size;
  const size_t ws_needed = (size_t)2048 * 1536 * sizeof(float);   // 12.58 MB
  if (ws_size >= ws_needed) {
    tfield_partial<<<dim3(2048), dim3(256), 0, stream>>>(
        (const float*)d_in[0], (const float*)d_in[1],
        (const float*)d_in[2], (const float*)d_in[3],
        (const float*)d_in[6], (const float*)d_in[7],
        (const float*)d_in[8], (const float*)d_in[9],
        (float*)d_ws);
    tfield_finish<<<dim3(256), dim3(512), 0, stream>>>(
        (const float*)d_ws, (const float*)d_in[10],
        (const float*)d_in[11], (float*)d_out);
  } else {
    tfield_kernel<<<dim3(256), dim3(512), 0, stream>>>(
        (const float*)d_in[0], (const float*)d_in[1],
        (const float*)d_in[2], (const float*)d_in[3],
        (const float*)d_in[6], (const float*)d_in[7],
        (const float*)d_in[8], (const float*)d_in[9],
        (const float*)d_in[10], (const float*)d_in[11],
        (float*)d_out);
  }
}

// Round 17
// 139.217 us; speedup vs baseline: 1.5433x; 1.5433x over previous
//
#include <hip/hip_runtime.h>
#include <hip/hip_bf16.h>

typedef __attribute__((ext_vector_type(8))) short short8;
typedef __attribute__((ext_vector_type(4))) float f32x4;
typedef __attribute__((ext_vector_type(4))) unsigned int u32x4;

#define MFMA16(A, B, C) __builtin_amdgcn_mfma_f32_16x16x32_bf16(A, B, C, 0, 0, 0)

__device__ __forceinline__ unsigned int pkbf(float lo, float hi) {
  unsigned int ul = (unsigned int)__bfloat16_as_ushort(__float2bfloat16(lo));
  unsigned int uh = (unsigned int)__bfloat16_as_ushort(__float2bfloat16(hi));
  return ul | (uh << 16);
}

union S8U { short8 s; u32x4 u; };
__device__ __forceinline__ short8 mk8(unsigned int a, unsigned int b,
                                      unsigned int c, unsigned int d) {
  S8U t; u32x4 v = {a, b, c, d}; t.u = v; return t.s;
}

constexpr float SU = 0.24430125595146f;   // (1/sqrt2)*sqrt(3/8)/sqrt(pi)
constexpr float SW = 0.34549414947134f;   // (1/sqrt2)*sqrt(3/4)/sqrt(pi)

// MFMA 16x16x32 bf16 layouts (HW-verified, rounds 2-3):
//   A: lane l holds A[row=l&15][k=8*(l>>4)+e];  B: lane l holds B[k=8*(l>>4)+e][col=l&15]
//   C/D: lane l reg v holds D[row=4*(l>>4)+v][col=l&15]

// ============ Kernel A: partial TP — round-10 config (measured best, 139.8us) ============
// grid 1024: bid = ((nq*2 + fh)*2 + ph); 256 threads (4 waves).
// FINAL-FORM NOTES (16 rounds of probing):
//  * REGISTER WINDOW: total arch+acc regs must be <= 256 for 2 waves/SIMD and
//    r10's ~190 is the only viable point. Forcing occupancy via __launch_bounds__
//    min-waves SPILLS (r5: 3.2x slower, r9: 2.6x). Adding register consumers
//    (W-in-regs r11/12, 3-deep prefetch r11) crosses 256 -> occupancy halves.
//  * cs-split (r16) doubles rbf readers; rbf (268MB) > L3 (256MB) -> FETCH x2,
//    net 1.6x slower despite 29% occupancy.
//  * setprio around MFMA: null (r13). DMA-ring via global_load_lds: neutral
//    (r15) - load depth is not the limiter; per-wave dependency stalls are.
//  * 12-byte global_load_lds is broken/unverified (r14 correctness failure).
__global__ __launch_bounds__(256) void tfield_partial(
    const float* __restrict__ rbf,  const float* __restrict__ uv,
    const float* __restrict__ inp1, const float* __restrict__ inp2,
    const float* __restrict__ W1,   const float* __restrict__ b1,
    const float* __restrict__ W2,   const float* __restrict__ b2,
    float* __restrict__ ws)
{
  __shared__ __align__(16) unsigned char pool[27008];
  unsigned int* wfrag = (unsigned int*)pool;             // 12 frags x 64 x 16B = 12288
  unsigned int* hbuf  = (unsigned int*)(pool + 12288);   // 4 waves x 16 rows x 128B
  float* ibuf  = (float*)(pool + 20480);                 // 4 waves x 2 slots x 192 f32
  float* biasL = (float*)(pool + 26624);                 // 64 b1 + 32 b2-half
  float* accL  = (float*)pool;                           // epilogue reuse

  const int tid = threadIdx.x;
  const int l   = tid & 63;
  const int w   = tid >> 6;     // wave 0..3
  const int g   = l >> 4;
  const int qh  = l & 15;
  const int bid = blockIdx.x;
  const int nq  = bid >> 2;
  const int fh  = (bid >> 1) & 1;
  const int ph  = bid & 1;
  const int n   = nq >> 4;
  const int q0  = (nq & 15) << 4;

  // ---- stage 12 W fragments (W1: 0..7, W2-half: 8..11) + biases ----
  #pragma unroll
  for (int k = 0; k < 3; ++k) {
    const int slot = tid + (k << 8);
    const int fi = slot >> 6;
    const int ll = slot & 63;
    const int gg = ll >> 4;
    const int qq = ll & 15;
    const float* src;
    if (fi < 8) {
      src = W1 + ((fi >> 1) * 16 + qq) * 64 + (fi & 1) * 32 + gg * 8;
    } else {
      const int fj = fi - 8;
      src = W2 + (((fh << 1) + (fj >> 1)) * 16 + qq) * 64 + (fj & 1) * 32 + gg * 8;
    }
    f32x4 x0 = *(const f32x4*)src;
    f32x4 x1 = *(const f32x4*)(src + 4);
    u32x4 vv = {pkbf(x0[0], x0[1]), pkbf(x0[2], x0[3]), pkbf(x1[0], x1[1]), pkbf(x1[2], x1[3])};
    *(u32x4*)(wfrag + ((fi << 6) + ll) * 4) = vv;
  }
  if (tid < 96) biasL[tid] = (tid < 64) ? b1[tid] : b2[(fh << 5) + tid - 64];
  __syncthreads();

  const float* bL1 = biasL;        // b1[f], f = 16mt+4g+v
  const float* bL2 = biasL + 64;   // b2[fh*32 + 16mt2l+4g+v]

  f32x4 accT[2][6];
  #pragma unroll
  for (int a = 0; a < 2; ++a)
    #pragma unroll
    for (int j = 0; j < 6; ++j) accT[a][j] = (f32x4){0.f, 0.f, 0.f, 0.f};

  const size_t nbase = (size_t)n * 256;
  const int pbase = (ph << 7) + w;   // wave w: p = pbase + 4*s, s in [0,32)

  const int sl = (l < 24) ? l : l - 24;
  const float* isrcb = (l < 24) ? inp1 : inp2;
  const int ioff = (sl >> 3) * 64 + (fh << 5) + ((sl & 7) << 2);

  unsigned int* hrow = hbuf + (w << 9) + (qh << 5);
  float* iw = ibuf + w * 384;          // 2 slots x 192 floats
  const int swz = qh & 7;

  // ---- prologue: L1(0) + stage inp(0)/h(0); prefetch step-1 data ----
  f32x4 rn0, rn1, rn2, rn3;
  { const float* rr = rbf + ((nbase + pbase) * 256 + q0 + qh) * 64 + (g << 3);
    rn0 = *(const f32x4*)rr;        rn1 = *(const f32x4*)(rr + 4);
    rn2 = *(const f32x4*)(rr + 32); rn3 = *(const f32x4*)(rr + 36); }
  f32x4 stage_v = {0.f, 0.f, 0.f, 0.f};
  if (l < 48) stage_v = *(const f32x4*)(isrcb + (nbase + pbase) * 192 + ioff);
  float uc0, uc1, uc2, un0, un1, un2;
  { const float* u = uv + ((nbase + pbase) * 256 + q0 + qh) * 3;
    uc0 = u[0]; uc1 = u[1]; uc2 = u[2]; }

  short8 rf0 = mk8(pkbf(rn0[0], rn0[1]), pkbf(rn0[2], rn0[3]), pkbf(rn1[0], rn1[1]), pkbf(rn1[2], rn1[3]));
  short8 rf1 = mk8(pkbf(rn2[0], rn2[1]), pkbf(rn2[2], rn2[3]), pkbf(rn3[0], rn3[1]), pkbf(rn3[2], rn3[3]));
  f32x4 h4[4];
  #pragma unroll
  for (int mt = 0; mt < 4; ++mt) {
    f32x4 c = *(const f32x4*)(bL1 + (mt << 4) + (g << 2));
    short8 a0 = *(const short8*)(wfrag + (((mt << 1) + 0) * 64 + l) * 4);
    short8 a1 = *(const short8*)(wfrag + (((mt << 1) + 1) * 64 + l) * 4);
    c = MFMA16(a0, rf0, c);
    c = MFMA16(a1, rf1, c);
    h4[mt] = c;
  }
  if (l < 48) *(f32x4*)(iw + (l << 2)) = stage_v;          // slot0 = inp(0)
  #pragma unroll
  for (int mt = 0; mt < 4; ++mt) {
    const float e0 = fmaxf(h4[mt][0], 0.f);
    const float e1 = fmaxf(h4[mt][1], 0.f);
    const float e2 = fmaxf(h4[mt][2], 0.f);
    const float e3 = fmaxf(h4[mt][3], 0.f);
    const int base = ((((mt << 1) + (g >> 1)) ^ swz) << 2) + ((g & 1) << 1);
    hrow[base]     = pkbf(e0, e1);
    hrow[base + 1] = pkbf(e2, e3);
  }
  short8 hb0 = *(const short8*)(hrow + (((0 + g) ^ swz) << 2));
  short8 hb1 = *(const short8*)(hrow + (((4 + g) ^ swz) << 2));
  // prefetch step-1 inputs
  { const float* rr = rbf + ((nbase + pbase + 4) * 256 + q0 + qh) * 64 + (g << 3);
    rn0 = *(const f32x4*)rr;        rn1 = *(const f32x4*)(rr + 4);
    rn2 = *(const f32x4*)(rr + 32); rn3 = *(const f32x4*)(rr + 36); }
  if (l < 48) stage_v = *(const f32x4*)(isrcb + (nbase + pbase + 4) * 192 + ioff);
  { const float* u = uv + ((nbase + pbase + 4) * 256 + q0 + qh) * 3;
    un0 = u[0]; un1 = u[1]; un2 = u[2]; }

  for (int s = 0; s < 32; ++s) {
    const int s2 = (s + 2 < 32) ? s + 2 : 31;    // clamped two-ahead prefetch index

    // A: pack rbf(s+1) and start L1 MFMA for step s+1 (independent of step-s work)
    rf0 = mk8(pkbf(rn0[0], rn0[1]), pkbf(rn0[2], rn0[3]), pkbf(rn1[0], rn1[1]), pkbf(rn1[2], rn1[3]));
    rf1 = mk8(pkbf(rn2[0], rn2[1]), pkbf(rn2[2], rn2[3]), pkbf(rn3[0], rn3[1]), pkbf(rn3[2], rn3[3]));
    #pragma unroll
    for (int mt = 0; mt < 4; ++mt) {
      f32x4 c = *(const f32x4*)(bL1 + (mt << 4) + (g << 2));
      short8 a0 = *(const short8*)(wfrag + (((mt << 1) + 0) * 64 + l) * 4);
      short8 a1 = *(const short8*)(wfrag + (((mt << 1) + 1) * 64 + l) * 4);
      c = MFMA16(a0, rf0, c);
      c = MFMA16(a1, rf1, c);
      h4[mt] = c;
    }
    // issue rbf(s+2) loads (consumed at top of next iteration)
    { const float* rr = rbf + ((nbase + pbase + (s2 << 2)) * 256 + q0 + qh) * 64 + (g << 3);
      rn0 = *(const f32x4*)rr;        rn1 = *(const f32x4*)(rr + 4);
      rn2 = *(const f32x4*)(rr + 32); rn3 = *(const f32x4*)(rr + 36); }

    // C: L2 MFMA for step s (uses hb read at end of previous iteration)
    f32x4 cc0, cc1;
    {
      f32x4 c = *(const f32x4*)(bL2 + (g << 2));
      short8 wa0 = *(const short8*)(wfrag + ((8 + 0) * 64 + l) * 4);
      short8 wa1 = *(const short8*)(wfrag + ((8 + 1) * 64 + l) * 4);
      c = MFMA16(wa0, hb0, c);
      c = MFMA16(wa1, hb1, c);
      cc0 = c;
      c = *(const f32x4*)(bL2 + 16 + (g << 2));
      wa0 = *(const short8*)(wfrag + ((8 + 2) * 64 + l) * 4);
      wa1 = *(const short8*)(wfrag + ((8 + 3) * 64 + l) * 4);
      c = MFMA16(wa0, hb0, c);
      c = MFMA16(wa1, hb1, c);
      cc1 = c;
    }

    // factors for step s; roll uv prefetch
    const float su  = SU * uc0;
    const float sv  = SU * uc1;
    const float swc = SW * uc2;
    uc0 = un0; uc1 = un1; uc2 = un2;
    { const float* u = uv + ((nbase + pbase + (s2 << 2)) * 256 + q0 + qh) * 3;
      un0 = u[0]; un1 = u[1]; un2 = u[2]; }

    // D: TP(s) in f32x4 vector form (packed v_pk_*_f32 math)
    const float* ib = iw + ((s & 1) * 192) + (g << 2);
    #pragma unroll
    for (int mt2l = 0; mt2l < 2; ++mt2l) {
      const f32x4 A0 = *(const f32x4*)(ib + (mt2l << 4));
      const f32x4 A1 = *(const f32x4*)(ib + (mt2l << 4) + 32);
      const f32x4 A2 = *(const f32x4*)(ib + (mt2l << 4) + 64);
      const f32x4 B0 = *(const f32x4*)(ib + (mt2l << 4) + 96);
      const f32x4 B1 = *(const f32x4*)(ib + (mt2l << 4) + 128);
      const f32x4 B2 = *(const f32x4*)(ib + (mt2l << 4) + 160);
      const f32x4 cc = mt2l ? cc1 : cc0;

      const f32x4 t1 = su * A1, t2 = sv * B1;
      const f32x4 t3 = su * B1, t4 = sv * A1;
      const f32x4 g10 = (t1 + t2) - swc * A0;
      const f32x4 g11 = su * (A0 + A2) - sv * (B0 - B2);
      const f32x4 g12 = (t1 - t2) + swc * A2;
      const f32x4 g20 = (t3 - t4) - swc * B0;
      const f32x4 g21 = sv * (A0 - A2) + su * (B0 + B2);
      const f32x4 g22 = (t3 + t4) + swc * B2;
      accT[mt2l][0] += cc * g10;
      accT[mt2l][1] += cc * g11;
      accT[mt2l][2] += cc * g12;
      accT[mt2l][3] += cc * g20;
      accT[mt2l][4] += cc * g21;
      accT[mt2l][5] += cc * g22;
    }

    // E: roll inp staging (write s+1 into the other slot; fetch s+2)
    if (l < 48) *(f32x4*)(iw + (((s + 1) & 1) * 192) + (l << 2)) = stage_v;
    if (l < 48) stage_v = *(const f32x4*)(isrcb + (nbase + pbase + (s2 << 2)) * 192 + ioff);

    // E2: relu/pack h(s+1) -> LDS transpose; read hb(s+1) for next iteration
    #pragma unroll
    for (int mt = 0; mt < 4; ++mt) {
      const float e0 = fmaxf(h4[mt][0], 0.f);
      const float e1 = fmaxf(h4[mt][1], 0.f);
      const float e2 = fmaxf(h4[mt][2], 0.f);
      const float e3 = fmaxf(h4[mt][3], 0.f);
      const int base = ((((mt << 1) + (g >> 1)) ^ swz) << 2) + ((g & 1) << 1);
      hrow[base]     = pkbf(e0, e1);
      hrow[base + 1] = pkbf(e2, e3);
    }
    hb0 = *(const short8*)(hrow + (((0 + g) ^ swz) << 2));
    hb1 = *(const short8*)(hrow + (((4 + g) ^ swz) << 2));
  }

  // ---- cross-wave reduce into accL [16 qh][32 fl][6], dump to ws ----
  __syncthreads();
  for (int i = tid; i < 3072; i += 256) accL[i] = 0.f;
  __syncthreads();
  for (int t = 0; t < 4; ++t) {
    if (w == t) {
      #pragma unroll
      for (int mt2l = 0; mt2l < 2; ++mt2l)
        #pragma unroll
        for (int v = 0; v < 4; ++v) {
          float* dst = accL + (((qh << 5) + (mt2l << 4) + (g << 2) + v) * 6);
          #pragma unroll
          for (int j = 0; j < 6; ++j) dst[j] += accT[mt2l][j][v];
        }
    }
    __syncthreads();
  }
  float* wp = ws + (size_t)bid * 3072;
  for (int i = tid; i < 3072; i += 256) wp[i] = accL[i];
}

// ============ Kernel B: combine 4 partials + normalize + project + gate ============
__global__ __launch_bounds__(512) void tfield_finish(
    const float* __restrict__ ws, const float* __restrict__ Wsi,
    const float* __restrict__ biasb, float* __restrict__ out)
{
  __shared__ __align__(16) float accL[6144];   // [16 qh][64 f][6]
  __shared__ __align__(16) float wsiT[4096];   // [64 f][64 g]

  const int tid = threadIdx.x;
  const int l   = tid & 63;
  const int w   = tid >> 6;
  const int nq  = blockIdx.x;
  const int n   = nq >> 4;
  const int q0  = (nq & 15) << 4;

  const float* c00 = ws + (size_t)(nq * 4 + 0) * 3072;  // fh0,ph0
  const float* c01 = c00 + 3072;                        // fh0,ph1
  const float* c10 = c00 + 6144;                        // fh1,ph0
  const float* c11 = c00 + 9216;                        // fh1,ph1
  for (int i = tid; i < 3072; i += 512) {
    const int qhh = i / 192;
    const int rem = i - qhh * 192;
    accL[qhh * 384 + rem]       = c00[i] + c01[i];
    accL[qhh * 384 + 192 + rem] = c10[i] + c11[i];
  }
  #pragma unroll
  for (int k = 0; k < 8; ++k) {
    const int f = (w << 3) + k;
    wsiT[(f << 6) + l] = Wsi[(l << 6) + f];
  }
  __syncthreads();

  #pragma unroll
  for (int rep = 0; rep < 2; ++rep) {
    const int qq = w + (rep << 3);
    float* xp = accL + ((qq << 6) + l) * 6;
    const float x0 = xp[0], x1 = xp[1], x2 = xp[2], x3 = xp[3], x4 = xp[4], x5 = xp[5];
    const float nrm = sqrtf(x0*x0 + x1*x1 + x2*x2 + x3*x3 + x4*x4 + x5*x5);
    const float sc = 1.f / (nrm + 1e-9f);
    xp[0] = x0 * sc; xp[1] = x1 * sc; xp[2] = x2 * sc;
    xp[3] = x3 * sc; xp[4] = x4 * sc; xp[5] = x5 * sc;
  }
  __syncthreads();

  const float bb = biasb[0];
  #pragma unroll
  for (int rep = 0; rep < 2; ++rep) {
    const int qq = w + (rep << 3);
    const float* arow = accL + (qq << 6) * 6;
    float pj0 = 0, pj1 = 0, pj2 = 0, pj3 = 0, pj4 = 0, pj5 = 0;
    for (int f = 0; f < 64; ++f) {
      const float wv = wsiT[(f << 6) + l];
      const float* ap = arow + f * 6;
      pj0 += ap[0] * wv; pj1 += ap[1] * wv; pj2 += ap[2] * wv;
      pj3 += ap[3] * wv; pj4 += ap[4] * wv; pj5 += ap[5] * wv;
    }
    const float s2 = pj0*pj0 + pj1*pj1 + pj2*pj2 + pj3*pj3 + pj4*pj4 + pj5*pj5;
    const float nl = fmaxf(sqrtf(s2) + bb, 0.f);
    const int q = q0 + qq;
    float* o1 = out + (size_t)((n * 256 + q) * 3) * 64 + l;   // out1[n,q,c,g]
    float* o2 = o1 + 786432;                                   // out2
    o1[0]   = pj0 * nl;
    o1[64]  = pj1 * nl;
    o1[128] = pj2 * nl;
    o2[0]   = pj3 * nl;
    o2[64]  = pj4 * nl;
    o2[128] = pj5 * nl;
  }
}

// ============ Fallback: round-4 monolithic kernel (used if ws too small) ============
__global__ __launch_bounds__(512) void tfield_kernel(
    const float* __restrict__ rbf,  const float* __restrict__ uv,
    const float* __restrict__ inp1, const float* __restrict__ inp2,
    const float* __restrict__ W1,   const float* __restrict__ b1,
    const float* __restrict__ W2,   const float* __restrict__ b2,
    const float* __restrict__ Wsi,  const float* __restrict__ biasb,
    float* __restrict__ out)
{
  __shared__ __align__(16) unsigned char pool[40960];
  unsigned int* wfrag = (unsigned int*)pool;
  unsigned int* hbuf  = (unsigned int*)(pool + 16384);
  float* accL = (float*)pool;
  float* wsiT = (float*)(pool + 24576);

  const int tid = threadIdx.x;
  const int l   = tid & 63;
  const int w   = tid >> 6;
  const int g   = l >> 4;
  const int qh  = l & 15;
  const int n   = blockIdx.x >> 4;
  const int q0  = (blockIdx.x & 15) << 4;

  {
    const int row = ((w >> 1) << 4) + qh;
    const int kb  = ((w & 1) << 5) + (g << 3);
    const float* s1 = W1 + row * 64 + kb;
    f32x4 x0 = *(const f32x4*)s1;
    f32x4 x1 = *(const f32x4*)(s1 + 4);
    u32x4 v1 = {pkbf(x0[0], x0[1]), pkbf(x0[2], x0[3]), pkbf(x1[0], x1[1]), pkbf(x1[2], x1[3])};
    *(u32x4*)(wfrag + ((w << 6) + l) * 4) = v1;
    const float* s2 = W2 + row * 64 + kb;
    x0 = *(const f32x4*)s2;
    x1 = *(const f32x4*)(s2 + 4);
    u32x4 v2 = {pkbf(x0[0], x0[1]), pkbf(x0[2], x0[3]), pkbf(x1[0], x1[1]), pkbf(x1[2], x1[3])};
    *(u32x4*)(wfrag + (((8 + w) << 6) + l) * 4) = v2;
  }
  __syncthreads();

  float accT[4][4][6];
  #pragma unroll
  for (int a = 0; a < 4; ++a)
    #pragma unroll
    for (int b = 0; b < 4; ++b)
      #pragma unroll
      for (int j = 0; j < 6; ++j) accT[a][b][j] = 0.f;

  const size_t nbase = (size_t)n * 256;
  const float* rr0 = rbf + ((nbase + w) * 256 + q0 + qh) * 64 + (g << 3);
  f32x4 nx0 = *(const f32x4*)(rr0);
  f32x4 nx1 = *(const f32x4*)(rr0 + 4);
  f32x4 nx2 = *(const f32x4*)(rr0 + 32);
  f32x4 nx3 = *(const f32x4*)(rr0 + 36);

  unsigned int* hrow = hbuf + ((w << 4) + qh) * 32;
  const int swz = qh & 7;

  for (int s = 0; s < 32; ++s) {
    const int p = (s << 3) + w;
    f32x4 r0 = nx0, r1 = nx1, r2 = nx2, r3 = nx3;
    {
      const int pn = (s < 31) ? p + 8 : p;
      const float* rr = rbf + ((nbase + pn) * 256 + q0 + qh) * 64 + (g << 3);
      nx0 = *(const f32x4*)(rr);
      nx1 = *(const f32x4*)(rr + 4);
      nx2 = *(const f32x4*)(rr + 32);
      nx3 = *(const f32x4*)(rr + 36);
    }
    const float* uvp = uv + ((nbase + p) * 256 + q0 + qh) * 3;
    const float su = SU * uvp[0];
    const float sv = SU * uvp[1];
    const float swc = SW * uvp[2];

    const short8 rf0 = mk8(pkbf(r0[0], r0[1]), pkbf(r0[2], r0[3]), pkbf(r1[0], r1[1]), pkbf(r1[2], r1[3]));
    const short8 rf1 = mk8(pkbf(r2[0], r2[1]), pkbf(r2[2], r2[3]), pkbf(r3[0], r3[1]), pkbf(r3[2], r3[3]));

    f32x4 h4[4];
    #pragma unroll
    for (int mt = 0; mt < 4; ++mt) {
      f32x4 c = *(const f32x4*)(b1 + (mt << 4) + (g << 2));
      short8 a0 = *(const short8*)(wfrag + (((mt << 1) + 0) * 64 + l) * 4);
      short8 a1 = *(const short8*)(wfrag + (((mt << 1) + 1) * 64 + l) * 4);
      c = MFMA16(a0, rf0, c);
      c = MFMA16(a1, rf1, c);
      h4[mt] = c;
    }
    #pragma unroll
    for (int mt = 0; mt < 4; ++mt) {
      const float e0 = fmaxf(h4[mt][0], 0.f);
      const float e1 = fmaxf(h4[mt][1], 0.f);
      const float e2 = fmaxf(h4[mt][2], 0.f);
      const float e3 = fmaxf(h4[mt][3], 0.f);
      const int base = ((((mt << 1) + (g >> 1)) ^ swz) << 2) + ((g & 1) << 1);
      hrow[base]     = pkbf(e0, e1);
      hrow[base + 1] = pkbf(e2, e3);
    }
    const short8 hb0 = *(const short8*)(hrow + (((0 + g) ^ swz) << 2));
    const short8 hb1 = *(const short8*)(hrow + (((4 + g) ^ swz) << 2));

    const float* i1p = inp1 + (nbase + p) * 192 + (g << 2);
    const float* i2p = inp2 + (nbase + p) * 192 + (g << 2);

    #pragma unroll
    for (int mt2 = 0; mt2 < 4; ++mt2) {
      f32x4 c = *(const f32x4*)(b2 + (mt2 << 4) + (g << 2));
      short8 wa0 = *(const short8*)(wfrag + ((8 + (mt2 << 1) + 0) * 64 + l) * 4);
      short8 wa1 = *(const short8*)(wfrag + ((8 + (mt2 << 1) + 1) * 64 + l) * 4);
      c = MFMA16(wa0, hb0, c);
      c = MFMA16(wa1, hb1, c);

      const int fo = mt2 << 4;
      const f32x4 A0 = *(const f32x4*)(i1p + fo);
      const f32x4 A1 = *(const f32x4*)(i1p + fo + 64);
      const f32x4 A2 = *(const f32x4*)(i1p + fo + 128);
      const f32x4 B0 = *(const f32x4*)(i2p + fo);
      const f32x4 B1 = *(const f32x4*)(i2p + fo + 64);
      const f32x4 B2 = *(const f32x4*)(i2p + fo + 128);
      const f32x4 a02p = A0 + A2, a02m = A0 - A2;
      const f32x4 b02p = B0 + B2, b02m = B0 - B2;

      #pragma unroll
      for (int v = 0; v < 4; ++v) {
        const float R = c[v];
        const float pua1 = su * A1[v], pvb1 = sv * B1[v];
        const float pub1 = su * B1[v], pva1 = sv * A1[v];
        const float g10 = pua1 - swc * A0[v] + pvb1;
        const float g11 = su * a02p[v] - sv * b02m[v];
        const float g12 = swc * A2[v] + pua1 - pvb1;
        const float g20 = pub1 - swc * B0[v] - pva1;
        const float g21 = sv * a02m[v] + su * b02p[v];
        const float g22 = swc * B2[v] + pub1 + pva1;
        accT[mt2][v][0] += R * g10;
        accT[mt2][v][1] += R * g11;
        accT[mt2][v][2] += R * g12;
        accT[mt2][v][3] += R * g20;
        accT[mt2][v][4] += R * g21;
        accT[mt2][v][5] += R * g22;
      }
    }
  }

  __syncthreads();
  for (int i = tid; i < 16 * 64 * 6; i += 512) accL[i] = 0.f;
  #pragma unroll
  for (int k = 0; k < 8; ++k) {
    const int f = (w << 3) + k;
    wsiT[(f << 6) + l] = Wsi[(l << 6) + f];
  }
  __syncthreads();

  for (int t = 0; t < 8; ++t) {
    if (w == t) {
      #pragma unroll
      for (int mt2 = 0; mt2 < 4; ++mt2)
        #pragma unroll
        for (int v = 0; v < 4; ++v) {
          float* dst = accL + (((qh << 6) + (mt2 << 4) + (g << 2) + v) * 6);
          #pragma unroll
          for (int j = 0; j < 6; ++j) dst[j] += accT[mt2][v][j];
        }
    }
    __syncthreads();
  }

  #pragma unroll
  for (int rep = 0; rep < 2; ++rep) {
    const int qq = w + (rep << 3);
    float* xp = accL + ((qq << 6) + l) * 6;
    const float x0 = xp[0], x1 = xp[1], x2 = xp[2], x3 = xp[3], x4 = xp[4], x5 = xp[5];
    const float nrm = sqrtf(x0*x0 + x1*x1 + x2*x2 + x3*x3 + x4*x4 + x5*x5);
    const float sc = 1.f / (nrm + 1e-9f);
    xp[0] = x0 * sc; xp[1] = x1 * sc; xp[2] = x2 * sc;
    xp[3] = x3 * sc; xp[4] = x4 * sc; xp[5] = x5 * sc;
  }
  __syncthreads();

  const float bb = biasb[0];
  #pragma unroll
  for (int rep = 0; rep < 2; ++rep) {
    const int qq = w + (rep << 3);
    const float* arow = accL + (qq << 6) * 6;
    float pj0 = 0, pj1 = 0, pj2 = 0, pj3 = 0, pj4 = 0, pj5 = 0;
    for (int f = 0; f < 64; ++f) {
      const float wv = wsiT[(f << 6) + l];
      const float* ap = arow + f * 6;
      pj0 += ap[0] * wv; pj1 += ap[1] * wv; pj2 += ap[2] * wv;
      pj3 += ap[3] * wv; pj4 += ap[4] * wv; pj5 += ap[5] * wv;
    }
    const float s2 = pj0*pj0 + pj1*pj1 + pj2*pj2 + pj3*pj3 + pj4*pj4 + pj5*pj5;
    const float nl = fmaxf(sqrtf(s2) + bb, 0.f);
    const int q = q0 + qq;
    float* o1 = out + (size_t)((n * 256 + q) * 3) * 64 + l;
    float* o2 = o1 + 786432;
    o1[0]   = pj0 * nl;
    o1[64]  = pj1 * nl;
    o1[128] = pj2 * nl;
    o2[0]   = pj3 * nl;
    o2[64]  = pj4 * nl;
    o2[128] = pj5 * nl;
  }
}

extern "C" void kernel_launch(void* const* d_in, const int* in_sizes, int n_in,
                              void* d_out, int out_size, void* d_ws, size_t ws_size,
                              hipStream_t stream) {
  (void)in_sizes; (void)n_in; (void)out_size;
  const size_t ws_needed = (size_t)1024 * 3072 * sizeof(float);   // 12.58 MB
  if (ws_size >= ws_needed) {
    tfield_partial<<<dim3(1024), dim3(256), 0, stream>>>(
        (const float*)d_in[0], (const float*)d_in[1],
        (const float*)d_in[2], (const float*)d_in[3],
        (const float*)d_in[6], (const float*)d_in[7],
        (const float*)d_in[8], (const float*)d_in[9],
        (float*)d_ws);
    tfield_finish<<<dim3(256), dim3(512), 0, stream>>>(
        (const float*)d_ws, (const float*)d_in[10],
        (const float*)d_in[11], (float*)d_out);
  } else {
    tfield_kernel<<<dim3(256), dim3(512), 0, stream>>>(
        (const float*)d_in[0], (const float*)d_in[1],
        (const float*)d_in[2], (const float*)d_in[3],
        (const float*)d_in[6], (const float*)d_in[7],
        (const float*)d_in[8], (const float*)d_in[9],
        (const float*)d_in[10], (const float*)d_in[11],
        (float*)d_out);
  }
}

// Round 18
// 124.480 us; speedup vs baseline: 1.7260x; 1.1184x over previous
//
#include <hip/hip_runtime.h>
#include <hip/hip_bf16.h>

typedef __attribute__((ext_vector_type(8))) short short8;
typedef __attribute__((ext_vector_type(4))) float f32x4;
typedef __attribute__((ext_vector_type(4))) unsigned int u32x4;

#define MFMA16(A, B, C) __builtin_amdgcn_mfma_f32_16x16x32_bf16(A, B, C, 0, 0, 0)

__device__ __forceinline__ unsigned int pkbf(float lo, float hi) {
  unsigned int ul = (unsigned int)__bfloat16_as_ushort(__float2bfloat16(lo));
  unsigned int uh = (unsigned int)__bfloat16_as_ushort(__float2bfloat16(hi));
  return ul | (uh << 16);
}

union S8U { short8 s; u32x4 u; };
__device__ __forceinline__ short8 mk8(unsigned int a, unsigned int b,
                                      unsigned int c, unsigned int d) {
  S8U t; u32x4 v = {a, b, c, d}; t.u = v; return t.s;
}

constexpr float SU = 0.24430125595146f;   // (1/sqrt2)*sqrt(3/8)/sqrt(pi)
constexpr float SW = 0.34549414947134f;   // (1/sqrt2)*sqrt(3/4)/sqrt(pi)

// MFMA 16x16x32 bf16 layouts (HW-verified, rounds 2-3):
//   A: lane l holds A[row=l&15][k=8*(l>>4)+e];  B: lane l holds B[k=8*(l>>4)+e][col=l&15]
//   C/D: lane l reg v holds D[row=4*(l>>4)+v][col=l&15]

// ============ Kernel A: partial TP — r10 config + XCD-aware work swizzle ============
// grid 1024: WORK id wid = ((nq*2 + fh)*2 + ph); 256 threads (4 waves).
// XCD SWIZZLE (T1): fh-twins (wid, wid+2) read IDENTICAL rbf/uv/inp. Default
// dispatch round-robins bids over 8 XCDs -> twins on different XCDs, each pays
// L3/HBM latency (the binding vmcnt stall: per-step chain ~600cy < load lat).
// Remap so XCD x owns work quads q in [32x, 32x+32): all 4 fh/ph variants of a
// quad co-locate -> twin rbf reads hit XCD-local L2. Bijective (1024%8==0).
// REGISTER WINDOW (r5/9/11/12): total arch+acc <= 256 for 2 waves/SIMD; r10's
// ~190 is the only viable point. All other levers measured: W-in-regs/deep
// prefetch halve occupancy, forced caps spill, setprio null, DMA-ring neutral,
// cs-split doubles FETCH (rbf 268MB > L3).
__global__ __launch_bounds__(256) void tfield_partial(
    const float* __restrict__ rbf,  const float* __restrict__ uv,
    const float* __restrict__ inp1, const float* __restrict__ inp2,
    const float* __restrict__ W1,   const float* __restrict__ b1,
    const float* __restrict__ W2,   const float* __restrict__ b2,
    float* __restrict__ ws)
{
  __shared__ __align__(16) unsigned char pool[27008];
  unsigned int* wfrag = (unsigned int*)pool;             // 12 frags x 64 x 16B = 12288
  unsigned int* hbuf  = (unsigned int*)(pool + 12288);   // 4 waves x 16 rows x 128B
  float* ibuf  = (float*)(pool + 20480);                 // 4 waves x 2 slots x 192 f32
  float* biasL = (float*)(pool + 26624);                 // 64 b1 + 32 b2-half
  float* accL  = (float*)pool;                           // epilogue reuse

  const int tid = threadIdx.x;
  const int l   = tid & 63;
  const int w   = tid >> 6;     // wave 0..3
  const int g   = l >> 4;
  const int qh  = l & 15;

  // XCD-aware work remap: dispatch bid -> work wid
  //   x = bid&7 (XCD under round-robin), s = bid>>3 (slot on that XCD)
  //   quad = (x<<5) | (s>>2)  (32 nq-quads per XCD), member = s&3
  const int bid = blockIdx.x;
  const int wid = ((((bid & 7) << 5) | (bid >> 5)) << 2) | ((bid >> 3) & 3);
  const int nq  = wid >> 2;
  const int fh  = (wid >> 1) & 1;
  const int ph  = wid & 1;
  const int n   = nq >> 4;
  const int q0  = (nq & 15) << 4;

  // ---- stage 12 W fragments (W1: 0..7, W2-half: 8..11) + biases ----
  #pragma unroll
  for (int k = 0; k < 3; ++k) {
    const int slot = tid + (k << 8);
    const int fi = slot >> 6;
    const int ll = slot & 63;
    const int gg = ll >> 4;
    const int qq = ll & 15;
    const float* src;
    if (fi < 8) {
      src = W1 + ((fi >> 1) * 16 + qq) * 64 + (fi & 1) * 32 + gg * 8;
    } else {
      const int fj = fi - 8;
      src = W2 + (((fh << 1) + (fj >> 1)) * 16 + qq) * 64 + (fj & 1) * 32 + gg * 8;
    }
    f32x4 x0 = *(const f32x4*)src;
    f32x4 x1 = *(const f32x4*)(src + 4);
    u32x4 vv = {pkbf(x0[0], x0[1]), pkbf(x0[2], x0[3]), pkbf(x1[0], x1[1]), pkbf(x1[2], x1[3])};
    *(u32x4*)(wfrag + ((fi << 6) + ll) * 4) = vv;
  }
  if (tid < 96) biasL[tid] = (tid < 64) ? b1[tid] : b2[(fh << 5) + tid - 64];
  __syncthreads();

  const float* bL1 = biasL;        // b1[f], f = 16mt+4g+v
  const float* bL2 = biasL + 64;   // b2[fh*32 + 16mt2l+4g+v]

  f32x4 accT[2][6];
  #pragma unroll
  for (int a = 0; a < 2; ++a)
    #pragma unroll
    for (int j = 0; j < 6; ++j) accT[a][j] = (f32x4){0.f, 0.f, 0.f, 0.f};

  const size_t nbase = (size_t)n * 256;
  const int pbase = (ph << 7) + w;   // wave w: p = pbase + 4*s, s in [0,32)

  const int sl = (l < 24) ? l : l - 24;
  const float* isrcb = (l < 24) ? inp1 : inp2;
  const int ioff = (sl >> 3) * 64 + (fh << 5) + ((sl & 7) << 2);

  unsigned int* hrow = hbuf + (w << 9) + (qh << 5);
  float* iw = ibuf + w * 384;          // 2 slots x 192 floats
  const int swz = qh & 7;

  // ---- prologue: L1(0) + stage inp(0)/h(0); prefetch step-1 data ----
  f32x4 rn0, rn1, rn2, rn3;
  { const float* rr = rbf + ((nbase + pbase) * 256 + q0 + qh) * 64 + (g << 3);
    rn0 = *(const f32x4*)rr;        rn1 = *(const f32x4*)(rr + 4);
    rn2 = *(const f32x4*)(rr + 32); rn3 = *(const f32x4*)(rr + 36); }
  f32x4 stage_v = {0.f, 0.f, 0.f, 0.f};
  if (l < 48) stage_v = *(const f32x4*)(isrcb + (nbase + pbase) * 192 + ioff);
  float uc0, uc1, uc2, un0, un1, un2;
  { const float* u = uv + ((nbase + pbase) * 256 + q0 + qh) * 3;
    uc0 = u[0]; uc1 = u[1]; uc2 = u[2]; }

  short8 rf0 = mk8(pkbf(rn0[0], rn0[1]), pkbf(rn0[2], rn0[3]), pkbf(rn1[0], rn1[1]), pkbf(rn1[2], rn1[3]));
  short8 rf1 = mk8(pkbf(rn2[0], rn2[1]), pkbf(rn2[2], rn2[3]), pkbf(rn3[0], rn3[1]), pkbf(rn3[2], rn3[3]));
  f32x4 h4[4];
  #pragma unroll
  for (int mt = 0; mt < 4; ++mt) {
    f32x4 c = *(const f32x4*)(bL1 + (mt << 4) + (g << 2));
    short8 a0 = *(const short8*)(wfrag + (((mt << 1) + 0) * 64 + l) * 4);
    short8 a1 = *(const short8*)(wfrag + (((mt << 1) + 1) * 64 + l) * 4);
    c = MFMA16(a0, rf0, c);
    c = MFMA16(a1, rf1, c);
    h4[mt] = c;
  }
  if (l < 48) *(f32x4*)(iw + (l << 2)) = stage_v;          // slot0 = inp(0)
  #pragma unroll
  for (int mt = 0; mt < 4; ++mt) {
    const float e0 = fmaxf(h4[mt][0], 0.f);
    const float e1 = fmaxf(h4[mt][1], 0.f);
    const float e2 = fmaxf(h4[mt][2], 0.f);
    const float e3 = fmaxf(h4[mt][3], 0.f);
    const int base = ((((mt << 1) + (g >> 1)) ^ swz) << 2) + ((g & 1) << 1);
    hrow[base]     = pkbf(e0, e1);
    hrow[base + 1] = pkbf(e2, e3);
  }
  short8 hb0 = *(const short8*)(hrow + (((0 + g) ^ swz) << 2));
  short8 hb1 = *(const short8*)(hrow + (((4 + g) ^ swz) << 2));
  // prefetch step-1 inputs
  { const float* rr = rbf + ((nbase + pbase + 4) * 256 + q0 + qh) * 64 + (g << 3);
    rn0 = *(const f32x4*)rr;        rn1 = *(const f32x4*)(rr + 4);
    rn2 = *(const f32x4*)(rr + 32); rn3 = *(const f32x4*)(rr + 36); }
  if (l < 48) stage_v = *(const f32x4*)(isrcb + (nbase + pbase + 4) * 192 + ioff);
  { const float* u = uv + ((nbase + pbase + 4) * 256 + q0 + qh) * 3;
    un0 = u[0]; un1 = u[1]; un2 = u[2]; }

  for (int s = 0; s < 32; ++s) {
    const int s2 = (s + 2 < 32) ? s + 2 : 31;    // clamped two-ahead prefetch index

    // A: pack rbf(s+1) and start L1 MFMA for step s+1 (independent of step-s work)
    rf0 = mk8(pkbf(rn0[0], rn0[1]), pkbf(rn0[2], rn0[3]), pkbf(rn1[0], rn1[1]), pkbf(rn1[2], rn1[3]));
    rf1 = mk8(pkbf(rn2[0], rn2[1]), pkbf(rn2[2], rn2[3]), pkbf(rn3[0], rn3[1]), pkbf(rn3[2], rn3[3]));
    #pragma unroll
    for (int mt = 0; mt < 4; ++mt) {
      f32x4 c = *(const f32x4*)(bL1 + (mt << 4) + (g << 2));
      short8 a0 = *(const short8*)(wfrag + (((mt << 1) + 0) * 64 + l) * 4);
      short8 a1 = *(const short8*)(wfrag + (((mt << 1) + 1) * 64 + l) * 4);
      c = MFMA16(a0, rf0, c);
      c = MFMA16(a1, rf1, c);
      h4[mt] = c;
    }
    // issue rbf(s+2) loads (consumed at top of next iteration)
    { const float* rr = rbf + ((nbase + pbase + (s2 << 2)) * 256 + q0 + qh) * 64 + (g << 3);
      rn0 = *(const f32x4*)rr;        rn1 = *(const f32x4*)(rr + 4);
      rn2 = *(const f32x4*)(rr + 32); rn3 = *(const f32x4*)(rr + 36); }

    // C: L2 MFMA for step s (uses hb read at end of previous iteration)
    f32x4 cc0, cc1;
    {
      f32x4 c = *(const f32x4*)(bL2 + (g << 2));
      short8 wa0 = *(const short8*)(wfrag + ((8 + 0) * 64 + l) * 4);
      short8 wa1 = *(const short8*)(wfrag + ((8 + 1) * 64 + l) * 4);
      c = MFMA16(wa0, hb0, c);
      c = MFMA16(wa1, hb1, c);
      cc0 = c;
      c = *(const f32x4*)(bL2 + 16 + (g << 2));
      wa0 = *(const short8*)(wfrag + ((8 + 2) * 64 + l) * 4);
      wa1 = *(const short8*)(wfrag + ((8 + 3) * 64 + l) * 4);
      c = MFMA16(wa0, hb0, c);
      c = MFMA16(wa1, hb1, c);
      cc1 = c;
    }

    // factors for step s; roll uv prefetch
    const float su  = SU * uc0;
    const float sv  = SU * uc1;
    const float swc = SW * uc2;
    uc0 = un0; uc1 = un1; uc2 = un2;
    { const float* u = uv + ((nbase + pbase + (s2 << 2)) * 256 + q0 + qh) * 3;
      un0 = u[0]; un1 = u[1]; un2 = u[2]; }

    // D: TP(s) in f32x4 vector form (packed v_pk_*_f32 math)
    const float* ib = iw + ((s & 1) * 192) + (g << 2);
    #pragma unroll
    for (int mt2l = 0; mt2l < 2; ++mt2l) {
      const f32x4 A0 = *(const f32x4*)(ib + (mt2l << 4));
      const f32x4 A1 = *(const f32x4*)(ib + (mt2l << 4) + 32);
      const f32x4 A2 = *(const f32x4*)(ib + (mt2l << 4) + 64);
      const f32x4 B0 = *(const f32x4*)(ib + (mt2l << 4) + 96);
      const f32x4 B1 = *(const f32x4*)(ib + (mt2l << 4) + 128);
      const f32x4 B2 = *(const f32x4*)(ib + (mt2l << 4) + 160);
      const f32x4 cc = mt2l ? cc1 : cc0;

      const f32x4 t1 = su * A1, t2 = sv * B1;
      const f32x4 t3 = su * B1, t4 = sv * A1;
      const f32x4 g10 = (t1 + t2) - swc * A0;
      const f32x4 g11 = su * (A0 + A2) - sv * (B0 - B2);
      const f32x4 g12 = (t1 - t2) + swc * A2;
      const f32x4 g20 = (t3 - t4) - swc * B0;
      const f32x4 g21 = sv * (A0 - A2) + su * (B0 + B2);
      const f32x4 g22 = (t3 + t4) + swc * B2;
      accT[mt2l][0] += cc * g10;
      accT[mt2l][1] += cc * g11;
      accT[mt2l][2] += cc * g12;
      accT[mt2l][3] += cc * g20;
      accT[mt2l][4] += cc * g21;
      accT[mt2l][5] += cc * g22;
    }

    // E: roll inp staging (write s+1 into the other slot; fetch s+2)
    if (l < 48) *(f32x4*)(iw + (((s + 1) & 1) * 192) + (l << 2)) = stage_v;
    if (l < 48) stage_v = *(const f32x4*)(isrcb + (nbase + pbase + (s2 << 2)) * 192 + ioff);

    // E2: relu/pack h(s+1) -> LDS transpose; read hb(s+1) for next iteration
    #pragma unroll
    for (int mt = 0; mt < 4; ++mt) {
      const float e0 = fmaxf(h4[mt][0], 0.f);
      const float e1 = fmaxf(h4[mt][1], 0.f);
      const float e2 = fmaxf(h4[mt][2], 0.f);
      const float e3 = fmaxf(h4[mt][3], 0.f);
      const int base = ((((mt << 1) + (g >> 1)) ^ swz) << 2) + ((g & 1) << 1);
      hrow[base]     = pkbf(e0, e1);
      hrow[base + 1] = pkbf(e2, e3);
    }
    hb0 = *(const short8*)(hrow + (((0 + g) ^ swz) << 2));
    hb1 = *(const short8*)(hrow + (((4 + g) ^ swz) << 2));
  }

  // ---- cross-wave reduce into accL [16 qh][32 fl][6], dump to ws ----
  __syncthreads();
  for (int i = tid; i < 3072; i += 256) accL[i] = 0.f;
  __syncthreads();
  for (int t = 0; t < 4; ++t) {
    if (w == t) {
      #pragma unroll
      for (int mt2l = 0; mt2l < 2; ++mt2l)
        #pragma unroll
        for (int v = 0; v < 4; ++v) {
          float* dst = accL + (((qh << 5) + (mt2l << 4) + (g << 2) + v) * 6);
          #pragma unroll
          for (int j = 0; j < 6; ++j) dst[j] += accT[mt2l][j][v];
        }
    }
    __syncthreads();
  }
  float* wp = ws + (size_t)wid * 3072;   // partials stored by WORK id
  for (int i = tid; i < 3072; i += 256) wp[i] = accL[i];
}

// ============ Kernel B: combine 4 partials + normalize + project + gate ============
__global__ __launch_bounds__(512) void tfield_finish(
    const float* __restrict__ ws, const float* __restrict__ Wsi,
    const float* __restrict__ biasb, float* __restrict__ out)
{
  __shared__ __align__(16) float accL[6144];   // [16 qh][64 f][6]
  __shared__ __align__(16) float wsiT[4096];   // [64 f][64 g]

  const int tid = threadIdx.x;
  const int l   = tid & 63;
  const int w   = tid >> 6;
  const int nq  = blockIdx.x;
  const int n   = nq >> 4;
  const int q0  = (nq & 15) << 4;

  const float* c00 = ws + (size_t)(nq * 4 + 0) * 3072;  // fh0,ph0
  const float* c01 = c00 + 3072;                        // fh0,ph1
  const float* c10 = c00 + 6144;                        // fh1,ph0
  const float* c11 = c00 + 9216;                        // fh1,ph1
  for (int i = tid; i < 3072; i += 512) {
    const int qhh = i / 192;
    const int rem = i - qhh * 192;
    accL[qhh * 384 + rem]       = c00[i] + c01[i];
    accL[qhh * 384 + 192 + rem] = c10[i] + c11[i];
  }
  #pragma unroll
  for (int k = 0; k < 8; ++k) {
    const int f = (w << 3) + k;
    wsiT[(f << 6) + l] = Wsi[(l << 6) + f];
  }
  __syncthreads();

  #pragma unroll
  for (int rep = 0; rep < 2; ++rep) {
    const int qq = w + (rep << 3);
    float* xp = accL + ((qq << 6) + l) * 6;
    const float x0 = xp[0], x1 = xp[1], x2 = xp[2], x3 = xp[3], x4 = xp[4], x5 = xp[5];
    const float nrm = sqrtf(x0*x0 + x1*x1 + x2*x2 + x3*x3 + x4*x4 + x5*x5);
    const float sc = 1.f / (nrm + 1e-9f);
    xp[0] = x0 * sc; xp[1] = x1 * sc; xp[2] = x2 * sc;
    xp[3] = x3 * sc; xp[4] = x4 * sc; xp[5] = x5 * sc;
  }
  __syncthreads();

  const float bb = biasb[0];
  #pragma unroll
  for (int rep = 0; rep < 2; ++rep) {
    const int qq = w + (rep << 3);
    const float* arow = accL + (qq << 6) * 6;
    float pj0 = 0, pj1 = 0, pj2 = 0, pj3 = 0, pj4 = 0, pj5 = 0;
    for (int f = 0; f < 64; ++f) {
      const float wv = wsiT[(f << 6) + l];
      const float* ap = arow + f * 6;
      pj0 += ap[0] * wv; pj1 += ap[1] * wv; pj2 += ap[2] * wv;
      pj3 += ap[3] * wv; pj4 += ap[4] * wv; pj5 += ap[5] * wv;
    }
    const float s2 = pj0*pj0 + pj1*pj1 + pj2*pj2 + pj3*pj3 + pj4*pj4 + pj5*pj5;
    const float nl = fmaxf(sqrtf(s2) + bb, 0.f);
    const int q = q0 + qq;
    float* o1 = out + (size_t)((n * 256 + q) * 3) * 64 + l;   // out1[n,q,c,g]
    float* o2 = o1 + 786432;                                   // out2
    o1[0]   = pj0 * nl;
    o1[64]  = pj1 * nl;
    o1[128] = pj2 * nl;
    o2[0]   = pj3 * nl;
    o2[64]  = pj4 * nl;
    o2[128] = pj5 * nl;
  }
}

// ============ Fallback: round-4 monolithic kernel (used if ws too small) ============
__global__ __launch_bounds__(512) void tfield_kernel(
    const float* __restrict__ rbf,  const float* __restrict__ uv,
    const float* __restrict__ inp1, const float* __restrict__ inp2,
    const float* __restrict__ W1,   const float* __restrict__ b1,
    const float* __restrict__ W2,   const float* __restrict__ b2,
    const float* __restrict__ Wsi,  const float* __restrict__ biasb,
    float* __restrict__ out)
{
  __shared__ __align__(16) unsigned char pool[40960];
  unsigned int* wfrag = (unsigned int*)pool;
  unsigned int* hbuf  = (unsigned int*)(pool + 16384);
  float* accL = (float*)pool;
  float* wsiT = (float*)(pool + 24576);

  const int tid = threadIdx.x;
  const int l   = tid & 63;
  const int w   = tid >> 6;
  const int g   = l >> 4;
  const int qh  = l & 15;
  const int n   = blockIdx.x >> 4;
  const int q0  = (blockIdx.x & 15) << 4;

  {
    const int row = ((w >> 1) << 4) + qh;
    const int kb  = ((w & 1) << 5) + (g << 3);
    const float* s1 = W1 + row * 64 + kb;
    f32x4 x0 = *(const f32x4*)s1;
    f32x4 x1 = *(const f32x4*)(s1 + 4);
    u32x4 v1 = {pkbf(x0[0], x0[1]), pkbf(x0[2], x0[3]), pkbf(x1[0], x1[1]), pkbf(x1[2], x1[3])};
    *(u32x4*)(wfrag + ((w << 6) + l) * 4) = v1;
    const float* s2 = W2 + row * 64 + kb;
    x0 = *(const f32x4*)s2;
    x1 = *(const f32x4*)(s2 + 4);
    u32x4 v2 = {pkbf(x0[0], x0[1]), pkbf(x0[2], x0[3]), pkbf(x1[0], x1[1]), pkbf(x1[2], x1[3])};
    *(u32x4*)(wfrag + (((8 + w) << 6) + l) * 4) = v2;
  }
  __syncthreads();

  float accT[4][4][6];
  #pragma unroll
  for (int a = 0; a < 4; ++a)
    #pragma unroll
    for (int b = 0; b < 4; ++b)
      #pragma unroll
      for (int j = 0; j < 6; ++j) accT[a][b][j] = 0.f;

  const size_t nbase = (size_t)n * 256;
  const float* rr0 = rbf + ((nbase + w) * 256 + q0 + qh) * 64 + (g << 3);
  f32x4 nx0 = *(const f32x4*)(rr0);
  f32x4 nx1 = *(const f32x4*)(rr0 + 4);
  f32x4 nx2 = *(const f32x4*)(rr0 + 32);
  f32x4 nx3 = *(const f32x4*)(rr0 + 36);

  unsigned int* hrow = hbuf + ((w << 4) + qh) * 32;
  const int swz = qh & 7;

  for (int s = 0; s < 32; ++s) {
    const int p = (s << 3) + w;
    f32x4 r0 = nx0, r1 = nx1, r2 = nx2, r3 = nx3;
    {
      const int pn = (s < 31) ? p + 8 : p;
      const float* rr = rbf + ((nbase + pn) * 256 + q0 + qh) * 64 + (g << 3);
      nx0 = *(const f32x4*)(rr);
      nx1 = *(const f32x4*)(rr + 4);
      nx2 = *(const f32x4*)(rr + 32);
      nx3 = *(const f32x4*)(rr + 36);
    }
    const float* uvp = uv + ((nbase + p) * 256 + q0 + qh) * 3;
    const float su = SU * uvp[0];
    const float sv = SU * uvp[1];
    const float swc = SW * uvp[2];

    const short8 rf0 = mk8(pkbf(r0[0], r0[1]), pkbf(r0[2], r0[3]), pkbf(r1[0], r1[1]), pkbf(r1[2], r1[3]));
    const short8 rf1 = mk8(pkbf(r2[0], r2[1]), pkbf(r2[2], r2[3]), pkbf(r3[0], r3[1]), pkbf(r3[2], r3[3]));

    f32x4 h4[4];
    #pragma unroll
    for (int mt = 0; mt < 4; ++mt) {
      f32x4 c = *(const f32x4*)(b1 + (mt << 4) + (g << 2));
      short8 a0 = *(const short8*)(wfrag + (((mt << 1) + 0) * 64 + l) * 4);
      short8 a1 = *(const short8*)(wfrag + (((mt << 1) + 1) * 64 + l) * 4);
      c = MFMA16(a0, rf0, c);
      c = MFMA16(a1, rf1, c);
      h4[mt] = c;
    }
    #pragma unroll
    for (int mt = 0; mt < 4; ++mt) {
      const float e0 = fmaxf(h4[mt][0], 0.f);
      const float e1 = fmaxf(h4[mt][1], 0.f);
      const float e2 = fmaxf(h4[mt][2], 0.f);
      const float e3 = fmaxf(h4[mt][3], 0.f);
      const int base = ((((mt << 1) + (g >> 1)) ^ swz) << 2) + ((g & 1) << 1);
      hrow[base]     = pkbf(e0, e1);
      hrow[base + 1] = pkbf(e2, e3);
    }
    const short8 hb0 = *(const short8*)(hrow + (((0 + g) ^ swz) << 2));
    const short8 hb1 = *(const short8*)(hrow + (((4 + g) ^ swz) << 2));

    const float* i1p = inp1 + (nbase + p) * 192 + (g << 2);
    const float* i2p = inp2 + (nbase + p) * 192 + (g << 2);

    #pragma unroll
    for (int mt2 = 0; mt2 < 4; ++mt2) {
      f32x4 c = *(const f32x4*)(b2 + (mt2 << 4) + (g << 2));
      short8 wa0 = *(const short8*)(wfrag + ((8 + (mt2 << 1) + 0) * 64 + l) * 4);
      short8 wa1 = *(const short8*)(wfrag + ((8 + (mt2 << 1) + 1) * 64 + l) * 4);
      c = MFMA16(wa0, hb0, c);
      c = MFMA16(wa1, hb1, c);

      const int fo = mt2 << 4;
      const f32x4 A0 = *(const f32x4*)(i1p + fo);
      const f32x4 A1 = *(const f32x4*)(i1p + fo + 64);
      const f32x4 A2 = *(const f32x4*)(i1p + fo + 128);
      const f32x4 B0 = *(const f32x4*)(i2p + fo);
      const f32x4 B1 = *(const f32x4*)(i2p + fo + 64);
      const f32x4 B2 = *(const f32x4*)(i2p + fo + 128);
      const f32x4 a02p = A0 + A2, a02m = A0 - A2;
      const f32x4 b02p = B0 + B2, b02m = B0 - B2;

      #pragma unroll
      for (int v = 0; v < 4; ++v) {
        const float R = c[v];
        const float pua1 = su * A1[v], pvb1 = sv * B1[v];
        const float pub1 = su * B1[v], pva1 = sv * A1[v];
        const float g10 = pua1 - swc * A0[v] + pvb1;
        const float g11 = su * a02p[v] - sv * b02m[v];
        const float g12 = swc * A2[v] + pua1 - pvb1;
        const float g20 = pub1 - swc * B0[v] - pva1;
        const float g21 = sv * a02m[v] + su * b02p[v];
        const float g22 = swc * B2[v] + pub1 + pva1;
        accT[mt2][v][0] += R * g10;
        accT[mt2][v][1] += R * g11;
        accT[mt2][v][2] += R * g12;
        accT[mt2][v][3] += R * g20;
        accT[mt2][v][4] += R * g21;
        accT[mt2][v][5] += R * g22;
      }
    }
  }

  __syncthreads();
  for (int i = tid; i < 16 * 64 * 6; i += 512) accL[i] = 0.f;
  #pragma unroll
  for (int k = 0; k < 8; ++k) {
    const int f = (w << 3) + k;
    wsiT[(f << 6) + l] = Wsi[(l << 6) + f];
  }
  __syncthreads();

  for (int t = 0; t < 8; ++t) {
    if (w == t) {
      #pragma unroll
      for (int mt2 = 0; mt2 < 4; ++mt2)
        #pragma unroll
        for (int v = 0; v < 4; ++v) {
          float* dst = accL + (((qh << 6) + (mt2 << 4) + (g << 2) + v) * 6);
          #pragma unroll
          for (int j = 0; j < 6; ++j) dst[j] += accT[mt2][v][j];
        }
    }
    __syncthreads();
  }

  #pragma unroll
  for (int rep = 0; rep < 2; ++rep) {
    const int qq = w + (rep << 3);
    float* xp = accL + ((qq << 6) + l) * 6;
    const float x0 = xp[0], x1 = xp[1], x2 = xp[2], x3 = xp[3], x4 = xp[4], x5 = xp[5];
    const float nrm = sqrtf(x0*x0 + x1*x1 + x2*x2 + x3*x3 + x4*x4 + x5*x5);
    const float sc = 1.f / (nrm + 1e-9f);
    xp[0] = x0 * sc; xp[1] = x1 * sc; xp[2] = x2 * sc;
    xp[3] = x3 * sc; xp[4] = x4 * sc; xp[5] = x5 * sc;
  }
  __syncthreads();

  const float bb = biasb[0];
  #pragma unroll
  for (int rep = 0; rep < 2; ++rep) {
    const int qq = w + (rep << 3);
    const float* arow = accL + (qq << 6) * 6;
    float pj0 = 0, pj1 = 0, pj2 = 0, pj3 = 0, pj4 = 0, pj5 = 0;
    for (int f = 0; f < 64; ++f) {
      const float wv = wsiT[(f << 6) + l];
      const float* ap = arow + f * 6;
      pj0 += ap[0] * wv; pj1 += ap[1] * wv; pj2 += ap[2] * wv;
      pj3 += ap[3] * wv; pj4 += ap[4] * wv; pj5 += ap[5] * wv;
    }
    const float s2 = pj0*pj0 + pj1*pj1 + pj2*pj2 + pj3*pj3 + pj4*pj4 + pj5*pj5;
    const float nl = fmaxf(sqrtf(s2) + bb, 0.f);
    const int q = q0 + qq;
    float* o1 = out + (size_t)((n * 256 + q) * 3) * 64 + l;
    float* o2 = o1 + 786432;
    o1[0]   = pj0 * nl;
    o1[64]  = pj1 * nl;
    o1[128] = pj2 * nl;
    o2[0]   = pj3 * nl;
    o2[64]  = pj4 * nl;
    o2[128] = pj5 * nl;
  }
}

extern "C" void kernel_launch(void* const* d_in, const int* in_sizes, int n_in,
                              void* d_out, int out_size, void* d_ws, size_t ws_size,
                              hipStream_t stream) {
  (void)in_sizes; (void)n_in; (void)out_size;
  const size_t ws_needed = (size_t)1024 * 3072 * sizeof(float);   // 12.58 MB
  if (ws_size >= ws_needed) {
    tfield_partial<<<dim3(1024), dim3(256), 0, stream>>>(
        (const float*)d_in[0], (const float*)d_in[1],
        (const float*)d_in[2], (const float*)d_in[3],
        (const float*)d_in[6], (const float*)d_in[7],
        (const float*)d_in[8], (const float*)d_in[9],
        (float*)d_ws);
    tfield_finish<<<dim3(256), dim3(512), 0, stream>>>(
        (const float*)d_ws, (const float*)d_in[10],
        (const float*)d_in[11], (float*)d_out);
  } else {
    tfield_kernel<<<dim3(256), dim3(512), 0, stream>>>(
        (const float*)d_in[0], (const float*)d_in[1],
        (const float*)d_in[2], (const float*)d_in[3],
        (const float*)d_in[6], (const float*)d_in[7],
        (const float*)d_in[8], (const float*)d_in[9],
        (const float*)d_in[10], (const float*)d_in[11],
        (float*)d_out);
  }
}

// Round 19
// 117.582 us; speedup vs baseline: 1.8273x; 1.0587x over previous
//
#include <hip/hip_runtime.h>
#include <hip/hip_bf16.h>

typedef __attribute__((ext_vector_type(8))) short short8;
typedef __attribute__((ext_vector_type(4))) float f32x4;
typedef __attribute__((ext_vector_type(4))) unsigned int u32x4;

#define MFMA16(A, B, C) __builtin_amdgcn_mfma_f32_16x16x32_bf16(A, B, C, 0, 0, 0)

__device__ __forceinline__ unsigned int pkbf(float lo, float hi) {
  unsigned int ul = (unsigned int)__bfloat16_as_ushort(__float2bfloat16(lo));
  unsigned int uh = (unsigned int)__bfloat16_as_ushort(__float2bfloat16(hi));
  return ul | (uh << 16);
}

union S8U { short8 s; u32x4 u; };
__device__ __forceinline__ short8 mk8(unsigned int a, unsigned int b,
                                      unsigned int c, unsigned int d) {
  S8U t; u32x4 v = {a, b, c, d}; t.u = v; return t.s;
}

constexpr float SU = 0.24430125595146f;   // (1/sqrt2)*sqrt(3/8)/sqrt(pi)
constexpr float SW = 0.34549414947134f;   // (1/sqrt2)*sqrt(3/4)/sqrt(pi)

// MFMA 16x16x32 bf16 layouts (HW-verified, rounds 2-3):
//   A: lane l holds A[row=l&15][k=8*(l>>4)+e];  B: lane l holds B[k=8*(l>>4)+e][col=l&15]
//   C/D: lane l reg v holds D[row=4*(l>>4)+v][col=l&15]

// ============ Kernel A: partial TP — fh merged back + XCD swizzle ============
// grid 512: WORK id wid = nq*2 + ph; 256 threads (4 waves).
// r18's XCD swizzle won -11% (twin rbf reads -> L2 hits). This round removes
// the twin entirely: fh merged back into one block (accT[4][6] f32x4 = 96 acc
// regs; total ~240 <= 256 window from r5/9/11/12 probing) so the shared
// per-step work (rbf pack, L1 MFMA, relu+h-transpose, uv loads) is computed
// ONCE instead of twice. Canary: occupancy ~10% means we crossed 256 -> revert.
// XCD swizzle kept: XCD x owns wid in [64x,64x+64) -> 2 n-values per XCD
// (inp1/inp2 shared across the 16 q0-tiles of each n stay XCD-local).
__global__ __launch_bounds__(256) void tfield_partial(
    const float* __restrict__ rbf,  const float* __restrict__ uv,
    const float* __restrict__ inp1, const float* __restrict__ inp2,
    const float* __restrict__ W1,   const float* __restrict__ b1,
    const float* __restrict__ W2,   const float* __restrict__ b2,
    float* __restrict__ ws)
{
  // LDS: wfrag 16384 | hbuf 8192 | ibuf 12288 | biasL 512  = 37376 B
  __shared__ __align__(16) unsigned char pool[37376];
  unsigned int* wfrag = (unsigned int*)pool;             // 16 frags x 64 x 16B
  unsigned int* hbuf  = (unsigned int*)(pool + 16384);   // 4 waves x 16 rows x 128B
  float* ibuf  = (float*)(pool + 24576);                 // 4 waves x 2 slots x 384 f32
  float* biasL = (float*)(pool + 36864);                 // 64 b1 + 64 b2
  float* accL  = (float*)pool;                           // epilogue reuse (6144 f32)

  const int tid = threadIdx.x;
  const int l   = tid & 63;
  const int w   = tid >> 6;     // wave 0..3
  const int g   = l >> 4;
  const int qh  = l & 15;

  // XCD-aware remap: bid -> wid ; x = bid&7, k = bid>>3 ; wid = x*64 + k
  const int bid = blockIdx.x;
  const int wid = ((bid & 7) << 6) | (bid >> 3);
  const int nq  = wid >> 1;
  const int ph  = wid & 1;
  const int n   = nq >> 4;
  const int q0  = (nq & 15) << 4;

  // ---- stage 16 W fragments (W1: 0..7, W2: 8..15) + biases ----
  #pragma unroll
  for (int k = 0; k < 4; ++k) {
    const int slot = tid + (k << 8);
    const int fi = slot >> 6;
    const int ll = slot & 63;
    const int gg = ll >> 4;
    const int qq = ll & 15;
    const float* src;
    if (fi < 8) {
      src = W1 + ((fi >> 1) * 16 + qq) * 64 + (fi & 1) * 32 + gg * 8;
    } else {
      const int fj = fi - 8;
      src = W2 + ((fj >> 1) * 16 + qq) * 64 + (fj & 1) * 32 + gg * 8;
    }
    f32x4 x0 = *(const f32x4*)src;
    f32x4 x1 = *(const f32x4*)(src + 4);
    u32x4 vv = {pkbf(x0[0], x0[1]), pkbf(x0[2], x0[3]), pkbf(x1[0], x1[1]), pkbf(x1[2], x1[3])};
    *(u32x4*)(wfrag + ((fi << 6) + ll) * 4) = vv;
  }
  if (tid < 128) biasL[tid] = (tid < 64) ? b1[tid] : b2[tid - 64];
  __syncthreads();

  const float* bL1 = biasL;        // b1[f], f = 16mt+4g+v
  const float* bL2 = biasL + 64;   // b2[f2], f2 = 16mt2+4g+v

  f32x4 accT[4][6];
  #pragma unroll
  for (int a = 0; a < 4; ++a)
    #pragma unroll
    for (int j = 0; j < 6; ++j) accT[a][j] = (f32x4){0.f, 0.f, 0.f, 0.f};

  const size_t nbase = (size_t)n * 256;
  const int pbase = (ph << 7) + w;   // wave w: p = pbase + 4*s, s in [0,32)

  const int sl = (l < 24) ? l : l - 24;
  const float* isrcb = (l < 24) ? inp1 : inp2;
  const int coff = (sl >> 3) * 64 + ((sl & 7) << 2);   // c*64 + 4*(sl&7), f in [0,32)
  const int ldst = (l < 24 ? 0 : 192) + coff;          // LDS offset within slot

  unsigned int* hrow = hbuf + (w << 9) + (qh << 5);
  float* iw = ibuf + w * 768;          // 2 slots x 384 floats
  const int swz = qh & 7;

  // ---- prologue: L1(0) + stage inp(0)/h(0); prefetch step-1 data ----
  f32x4 rn0, rn1, rn2, rn3;
  { const float* rr = rbf + ((nbase + pbase) * 256 + q0 + qh) * 64 + (g << 3);
    rn0 = *(const f32x4*)rr;        rn1 = *(const f32x4*)(rr + 4);
    rn2 = *(const f32x4*)(rr + 32); rn3 = *(const f32x4*)(rr + 36); }
  f32x4 stage_v0 = {0.f,0.f,0.f,0.f}, stage_v1 = {0.f,0.f,0.f,0.f};
  if (l < 48) {
    const float* ip = isrcb + (nbase + pbase) * 192 + coff;
    stage_v0 = *(const f32x4*)ip;
    stage_v1 = *(const f32x4*)(ip + 32);
  }
  float uc0, uc1, uc2, un0, un1, un2;
  { const float* u = uv + ((nbase + pbase) * 256 + q0 + qh) * 3;
    uc0 = u[0]; uc1 = u[1]; uc2 = u[2]; }

  short8 rf0 = mk8(pkbf(rn0[0], rn0[1]), pkbf(rn0[2], rn0[3]), pkbf(rn1[0], rn1[1]), pkbf(rn1[2], rn1[3]));
  short8 rf1 = mk8(pkbf(rn2[0], rn2[1]), pkbf(rn2[2], rn2[3]), pkbf(rn3[0], rn3[1]), pkbf(rn3[2], rn3[3]));
  f32x4 h4[4];
  #pragma unroll
  for (int mt = 0; mt < 4; ++mt) {
    f32x4 c = *(const f32x4*)(bL1 + (mt << 4) + (g << 2));
    short8 a0 = *(const short8*)(wfrag + (((mt << 1) + 0) * 64 + l) * 4);
    short8 a1 = *(const short8*)(wfrag + (((mt << 1) + 1) * 64 + l) * 4);
    c = MFMA16(a0, rf0, c);
    c = MFMA16(a1, rf1, c);
    h4[mt] = c;
  }
  if (l < 48) {                        // slot0 = inp(0)
    *(f32x4*)(iw + ldst) = stage_v0;
    *(f32x4*)(iw + ldst + 32) = stage_v1;
  }
  #pragma unroll
  for (int mt = 0; mt < 4; ++mt) {
    const float e0 = fmaxf(h4[mt][0], 0.f);
    const float e1 = fmaxf(h4[mt][1], 0.f);
    const float e2 = fmaxf(h4[mt][2], 0.f);
    const float e3 = fmaxf(h4[mt][3], 0.f);
    const int base = ((((mt << 1) + (g >> 1)) ^ swz) << 2) + ((g & 1) << 1);
    hrow[base]     = pkbf(e0, e1);
    hrow[base + 1] = pkbf(e2, e3);
  }
  short8 hb0 = *(const short8*)(hrow + (((0 + g) ^ swz) << 2));
  short8 hb1 = *(const short8*)(hrow + (((4 + g) ^ swz) << 2));
  // prefetch step-1 inputs
  { const float* rr = rbf + ((nbase + pbase + 4) * 256 + q0 + qh) * 64 + (g << 3);
    rn0 = *(const f32x4*)rr;        rn1 = *(const f32x4*)(rr + 4);
    rn2 = *(const f32x4*)(rr + 32); rn3 = *(const f32x4*)(rr + 36); }
  if (l < 48) {
    const float* ip = isrcb + (nbase + pbase + 4) * 192 + coff;
    stage_v0 = *(const f32x4*)ip;
    stage_v1 = *(const f32x4*)(ip + 32);
  }
  { const float* u = uv + ((nbase + pbase + 4) * 256 + q0 + qh) * 3;
    un0 = u[0]; un1 = u[1]; un2 = u[2]; }

  for (int s = 0; s < 32; ++s) {
    const int s2 = (s + 2 < 32) ? s + 2 : 31;    // clamped two-ahead prefetch index

    // A: pack rbf(s+1) and start L1 MFMA for step s+1 (shared across all f2 now)
    rf0 = mk8(pkbf(rn0[0], rn0[1]), pkbf(rn0[2], rn0[3]), pkbf(rn1[0], rn1[1]), pkbf(rn1[2], rn1[3]));
    rf1 = mk8(pkbf(rn2[0], rn2[1]), pkbf(rn2[2], rn2[3]), pkbf(rn3[0], rn3[1]), pkbf(rn3[2], rn3[3]));
    #pragma unroll
    for (int mt = 0; mt < 4; ++mt) {
      f32x4 c = *(const f32x4*)(bL1 + (mt << 4) + (g << 2));
      short8 a0 = *(const short8*)(wfrag + (((mt << 1) + 0) * 64 + l) * 4);
      short8 a1 = *(const short8*)(wfrag + (((mt << 1) + 1) * 64 + l) * 4);
      c = MFMA16(a0, rf0, c);
      c = MFMA16(a1, rf1, c);
      h4[mt] = c;
    }
    // issue rbf(s+2) loads (consumed at top of next iteration)
    { const float* rr = rbf + ((nbase + pbase + (s2 << 2)) * 256 + q0 + qh) * 64 + (g << 3);
      rn0 = *(const f32x4*)rr;        rn1 = *(const f32x4*)(rr + 4);
      rn2 = *(const f32x4*)(rr + 32); rn3 = *(const f32x4*)(rr + 36); }

    // factors for step s; roll uv prefetch
    const float su  = SU * uc0;
    const float sv  = SU * uc1;
    const float swc = SW * uc2;
    uc0 = un0; uc1 = un1; uc2 = un2;
    { const float* u = uv + ((nbase + pbase + (s2 << 2)) * 256 + q0 + qh) * 3;
      un0 = u[0]; un1 = u[1]; un2 = u[2]; }

    // C+D: per f2-quadrant: L2 MFMA then TP accumulate (all 4 quadrants now)
    const float* ib = iw + ((s & 1) * 384);
    #pragma unroll
    for (int mt2 = 0; mt2 < 4; ++mt2) {
      f32x4 c = *(const f32x4*)(bL2 + (mt2 << 4) + (g << 2));
      short8 wa0 = *(const short8*)(wfrag + ((8 + (mt2 << 1) + 0) * 64 + l) * 4);
      short8 wa1 = *(const short8*)(wfrag + ((8 + (mt2 << 1) + 1) * 64 + l) * 4);
      c = MFMA16(wa0, hb0, c);
      c = MFMA16(wa1, hb1, c);   // R[f2 = 16mt2+4g+v][q = q0+qh]

      const int fo = (mt2 << 4) + (g << 2);
      const f32x4 A0 = *(const f32x4*)(ib + fo);
      const f32x4 A1 = *(const f32x4*)(ib + fo + 64);
      const f32x4 A2 = *(const f32x4*)(ib + fo + 128);
      const f32x4 B0 = *(const f32x4*)(ib + fo + 192);
      const f32x4 B1 = *(const f32x4*)(ib + fo + 256);
      const f32x4 B2 = *(const f32x4*)(ib + fo + 320);

      const f32x4 t1 = su * A1, t2 = sv * B1;
      const f32x4 t3 = su * B1, t4 = sv * A1;
      const f32x4 g10 = (t1 + t2) - swc * A0;
      const f32x4 g11 = su * (A0 + A2) - sv * (B0 - B2);
      const f32x4 g12 = (t1 - t2) + swc * A2;
      const f32x4 g20 = (t3 - t4) - swc * B0;
      const f32x4 g21 = sv * (A0 - A2) + su * (B0 + B2);
      const f32x4 g22 = (t3 + t4) + swc * B2;
      accT[mt2][0] += c * g10;
      accT[mt2][1] += c * g11;
      accT[mt2][2] += c * g12;
      accT[mt2][3] += c * g20;
      accT[mt2][4] += c * g21;
      accT[mt2][5] += c * g22;
    }

    // E: roll inp staging (write s+1 into the other slot; fetch s+2)
    if (l < 48) {
      float* dst = iw + (((s + 1) & 1) * 384) + ldst;
      *(f32x4*)dst = stage_v0;
      *(f32x4*)(dst + 32) = stage_v1;
      const float* ip = isrcb + (nbase + pbase + (s2 << 2)) * 192 + coff;
      stage_v0 = *(const f32x4*)ip;
      stage_v1 = *(const f32x4*)(ip + 32);
    }

    // E2: relu/pack h(s+1) -> LDS transpose; read hb(s+1) for next iteration
    #pragma unroll
    for (int mt = 0; mt < 4; ++mt) {
      const float e0 = fmaxf(h4[mt][0], 0.f);
      const float e1 = fmaxf(h4[mt][1], 0.f);
      const float e2 = fmaxf(h4[mt][2], 0.f);
      const float e3 = fmaxf(h4[mt][3], 0.f);
      const int base = ((((mt << 1) + (g >> 1)) ^ swz) << 2) + ((g & 1) << 1);
      hrow[base]     = pkbf(e0, e1);
      hrow[base + 1] = pkbf(e2, e3);
    }
    hb0 = *(const short8*)(hrow + (((0 + g) ^ swz) << 2));
    hb1 = *(const short8*)(hrow + (((4 + g) ^ swz) << 2));
  }

  // ---- cross-wave reduce into accL [16 qh][64 f2][6], dump to ws ----
  __syncthreads();
  for (int i = tid; i < 6144; i += 256) accL[i] = 0.f;
  __syncthreads();
  for (int t = 0; t < 4; ++t) {
    if (w == t) {
      #pragma unroll
      for (int mt2 = 0; mt2 < 4; ++mt2)
        #pragma unroll
        for (int v = 0; v < 4; ++v) {
          float* dst = accL + (((qh << 6) + (mt2 << 4) + (g << 2) + v) * 6);
          #pragma unroll
          for (int j = 0; j < 6; ++j) dst[j] += accT[mt2][j][v];
        }
    }
    __syncthreads();
  }
  float* wp = ws + (size_t)wid * 6144;   // partials stored by WORK id
  for (int i = tid; i < 6144; i += 256) wp[i] = accL[i];
}

// ============ Kernel B: combine 2 ph-partials + normalize + project + gate ============
__global__ __launch_bounds__(512) void tfield_finish(
    const float* __restrict__ ws, const float* __restrict__ Wsi,
    const float* __restrict__ biasb, float* __restrict__ out)
{
  __shared__ __align__(16) float accL[6144];   // [16 qh][64 f][6]
  __shared__ __align__(16) float wsiT[4096];   // [64 f][64 g]

  const int tid = threadIdx.x;
  const int l   = tid & 63;
  const int w   = tid >> 6;
  const int nq  = blockIdx.x;
  const int n   = nq >> 4;
  const int q0  = (nq & 15) << 4;

  const float* c0 = ws + (size_t)(nq * 2) * 6144;  // ph0
  const float* c1 = c0 + 6144;                     // ph1
  for (int i = tid; i < 6144; i += 512) accL[i] = c0[i] + c1[i];
  #pragma unroll
  for (int k = 0; k < 8; ++k) {
    const int f = (w << 3) + k;
    wsiT[(f << 6) + l] = Wsi[(l << 6) + f];
  }
  __syncthreads();

  #pragma unroll
  for (int rep = 0; rep < 2; ++rep) {
    const int qq = w + (rep << 3);
    float* xp = accL + ((qq << 6) + l) * 6;
    const float x0 = xp[0], x1 = xp[1], x2 = xp[2], x3 = xp[3], x4 = xp[4], x5 = xp[5];
    const float nrm = sqrtf(x0*x0 + x1*x1 + x2*x2 + x3*x3 + x4*x4 + x5*x5);
    const float sc = 1.f / (nrm + 1e-9f);
    xp[0] = x0 * sc; xp[1] = x1 * sc; xp[2] = x2 * sc;
    xp[3] = x3 * sc; xp[4] = x4 * sc; xp[5] = x5 * sc;
  }
  __syncthreads();

  const float bb = biasb[0];
  #pragma unroll
  for (int rep = 0; rep < 2; ++rep) {
    const int qq = w + (rep << 3);
    const float* arow = accL + (qq << 6) * 6;
    float pj0 = 0, pj1 = 0, pj2 = 0, pj3 = 0, pj4 = 0, pj5 = 0;
    for (int f = 0; f < 64; ++f) {
      const float wv = wsiT[(f << 6) + l];
      const float* ap = arow + f * 6;
      pj0 += ap[0] * wv; pj1 += ap[1] * wv; pj2 += ap[2] * wv;
      pj3 += ap[3] * wv; pj4 += ap[4] * wv; pj5 += ap[5] * wv;
    }
    const float s2 = pj0*pj0 + pj1*pj1 + pj2*pj2 + pj3*pj3 + pj4*pj4 + pj5*pj5;
    const float nl = fmaxf(sqrtf(s2) + bb, 0.f);
    const int q = q0 + qq;
    float* o1 = out + (size_t)((n * 256 + q) * 3) * 64 + l;   // out1[n,q,c,g]
    float* o2 = o1 + 786432;                                   // out2
    o1[0]   = pj0 * nl;
    o1[64]  = pj1 * nl;
    o1[128] = pj2 * nl;
    o2[0]   = pj3 * nl;
    o2[64]  = pj4 * nl;
    o2[128] = pj5 * nl;
  }
}

// ============ Fallback: round-4 monolithic kernel (used if ws too small) ============
__global__ __launch_bounds__(512) void tfield_kernel(
    const float* __restrict__ rbf,  const float* __restrict__ uv,
    const float* __restrict__ inp1, const float* __restrict__ inp2,
    const float* __restrict__ W1,   const float* __restrict__ b1,
    const float* __restrict__ W2,   const float* __restrict__ b2,
    const float* __restrict__ Wsi,  const float* __restrict__ biasb,
    float* __restrict__ out)
{
  __shared__ __align__(16) unsigned char pool[40960];
  unsigned int* wfrag = (unsigned int*)pool;
  unsigned int* hbuf  = (unsigned int*)(pool + 16384);
  float* accL = (float*)pool;
  float* wsiT = (float*)(pool + 24576);

  const int tid = threadIdx.x;
  const int l   = tid & 63;
  const int w   = tid >> 6;
  const int g   = l >> 4;
  const int qh  = l & 15;
  const int n   = blockIdx.x >> 4;
  const int q0  = (blockIdx.x & 15) << 4;

  {
    const int row = ((w >> 1) << 4) + qh;
    const int kb  = ((w & 1) << 5) + (g << 3);
    const float* s1 = W1 + row * 64 + kb;
    f32x4 x0 = *(const f32x4*)s1;
    f32x4 x1 = *(const f32x4*)(s1 + 4);
    u32x4 v1 = {pkbf(x0[0], x0[1]), pkbf(x0[2], x0[3]), pkbf(x1[0], x1[1]), pkbf(x1[2], x1[3])};
    *(u32x4*)(wfrag + ((w << 6) + l) * 4) = v1;
    const float* s2 = W2 + row * 64 + kb;
    x0 = *(const f32x4*)s2;
    x1 = *(const f32x4*)(s2 + 4);
    u32x4 v2 = {pkbf(x0[0], x0[1]), pkbf(x0[2], x0[3]), pkbf(x1[0], x1[1]), pkbf(x1[2], x1[3])};
    *(u32x4*)(wfrag + (((8 + w) << 6) + l) * 4) = v2;
  }
  __syncthreads();

  float accT[4][4][6];
  #pragma unroll
  for (int a = 0; a < 4; ++a)
    #pragma unroll
    for (int b = 0; b < 4; ++b)
      #pragma unroll
      for (int j = 0; j < 6; ++j) accT[a][b][j] = 0.f;

  const size_t nbase = (size_t)n * 256;
  const float* rr0 = rbf + ((nbase + w) * 256 + q0 + qh) * 64 + (g << 3);
  f32x4 nx0 = *(const f32x4*)(rr0);
  f32x4 nx1 = *(const f32x4*)(rr0 + 4);
  f32x4 nx2 = *(const f32x4*)(rr0 + 32);
  f32x4 nx3 = *(const f32x4*)(rr0 + 36);

  unsigned int* hrow = hbuf + ((w << 4) + qh) * 32;
  const int swz = qh & 7;

  for (int s = 0; s < 32; ++s) {
    const int p = (s << 3) + w;
    f32x4 r0 = nx0, r1 = nx1, r2 = nx2, r3 = nx3;
    {
      const int pn = (s < 31) ? p + 8 : p;
      const float* rr = rbf + ((nbase + pn) * 256 + q0 + qh) * 64 + (g << 3);
      nx0 = *(const f32x4*)(rr);
      nx1 = *(const f32x4*)(rr + 4);
      nx2 = *(const f32x4*)(rr + 32);
      nx3 = *(const f32x4*)(rr + 36);
    }
    const float* uvp = uv + ((nbase + p) * 256 + q0 + qh) * 3;
    const float su = SU * uvp[0];
    const float sv = SU * uvp[1];
    const float swc = SW * uvp[2];

    const short8 rf0 = mk8(pkbf(r0[0], r0[1]), pkbf(r0[2], r0[3]), pkbf(r1[0], r1[1]), pkbf(r1[2], r1[3]));
    const short8 rf1 = mk8(pkbf(r2[0], r2[1]), pkbf(r2[2], r2[3]), pkbf(r3[0], r3[1]), pkbf(r3[2], r3[3]));

    f32x4 h4[4];
    #pragma unroll
    for (int mt = 0; mt < 4; ++mt) {
      f32x4 c = *(const f32x4*)(b1 + (mt << 4) + (g << 2));
      short8 a0 = *(const short8*)(wfrag + (((mt << 1) + 0) * 64 + l) * 4);
      short8 a1 = *(const short8*)(wfrag + (((mt << 1) + 1) * 64 + l) * 4);
      c = MFMA16(a0, rf0, c);
      c = MFMA16(a1, rf1, c);
      h4[mt] = c;
    }
    #pragma unroll
    for (int mt = 0; mt < 4; ++mt) {
      const float e0 = fmaxf(h4[mt][0], 0.f);
      const float e1 = fmaxf(h4[mt][1], 0.f);
      const float e2 = fmaxf(h4[mt][2], 0.f);
      const float e3 = fmaxf(h4[mt][3], 0.f);
      const int base = ((((mt << 1) + (g >> 1)) ^ swz) << 2) + ((g & 1) << 1);
      hrow[base]     = pkbf(e0, e1);
      hrow[base + 1] = pkbf(e2, e3);
    }
    const short8 hb0 = *(const short8*)(hrow + (((0 + g) ^ swz) << 2));
    const short8 hb1 = *(const short8*)(hrow + (((4 + g) ^ swz) << 2));

    const float* i1p = inp1 + (nbase + p) * 192 + (g << 2);
    const float* i2p = inp2 + (nbase + p) * 192 + (g << 2);

    #pragma unroll
    for (int mt2 = 0; mt2 < 4; ++mt2) {
      f32x4 c = *(const f32x4*)(b2 + (mt2 << 4) + (g << 2));
      short8 wa0 = *(const short8*)(wfrag + ((8 + (mt2 << 1) + 0) * 64 + l) * 4);
      short8 wa1 = *(const short8*)(wfrag + ((8 + (mt2 << 1) + 1) * 64 + l) * 4);
      c = MFMA16(wa0, hb0, c);
      c = MFMA16(wa1, hb1, c);

      const int fo = mt2 << 4;
      const f32x4 A0 = *(const f32x4*)(i1p + fo);
      const f32x4 A1 = *(const f32x4*)(i1p + fo + 64);
      const f32x4 A2 = *(const f32x4*)(i1p + fo + 128);
      const f32x4 B0 = *(const f32x4*)(i2p + fo);
      const f32x4 B1 = *(const f32x4*)(i2p + fo + 64);
      const f32x4 B2 = *(const f32x4*)(i2p + fo + 128);
      const f32x4 a02p = A0 + A2, a02m = A0 - A2;
      const f32x4 b02p = B0 + B2, b02m = B0 - B2;

      #pragma unroll
      for (int v = 0; v < 4; ++v) {
        const float R = c[v];
        const float pua1 = su * A1[v], pvb1 = sv * B1[v];
        const float pub1 = su * B1[v], pva1 = sv * A1[v];
        const float g10 = pua1 - swc * A0[v] + pvb1;
        const float g11 = su * a02p[v] - sv * b02m[v];
        const float g12 = swc * A2[v] + pua1 - pvb1;
        const float g20 = pub1 - swc * B0[v] - pva1;
        const float g21 = sv * a02m[v] + su * b02p[v];
        const float g22 = swc * B2[v] + pub1 + pva1;
        accT[mt2][v][0] += R * g10;
        accT[mt2][v][1] += R * g11;
        accT[mt2][v][2] += R * g12;
        accT[mt2][v][3] += R * g20;
        accT[mt2][v][4] += R * g21;
        accT[mt2][v][5] += R * g22;
      }
    }
  }

  __syncthreads();
  for (int i = tid; i < 16 * 64 * 6; i += 512) accL[i] = 0.f;
  #pragma unroll
  for (int k = 0; k < 8; ++k) {
    const int f = (w << 3) + k;
    wsiT[(f << 6) + l] = Wsi[(l << 6) + f];
  }
  __syncthreads();

  for (int t = 0; t < 8; ++t) {
    if (w == t) {
      #pragma unroll
      for (int mt2 = 0; mt2 < 4; ++mt2)
        #pragma unroll
        for (int v = 0; v < 4; ++v) {
          float* dst = accL + (((qh << 6) + (mt2 << 4) + (g << 2) + v) * 6);
          #pragma unroll
          for (int j = 0; j < 6; ++j) dst[j] += accT[mt2][v][j];
        }
    }
    __syncthreads();
  }

  #pragma unroll
  for (int rep = 0; rep < 2; ++rep) {
    const int qq = w + (rep << 3);
    float* xp = accL + ((qq << 6) + l) * 6;
    const float x0 = xp[0], x1 = xp[1], x2 = xp[2], x3 = xp[3], x4 = xp[4], x5 = xp[5];
    const float nrm = sqrtf(x0*x0 + x1*x1 + x2*x2 + x3*x3 + x4*x4 + x5*x5);
    const float sc = 1.f / (nrm + 1e-9f);
    xp[0] = x0 * sc; xp[1] = x1 * sc; xp[2] = x2 * sc;
    xp[3] = x3 * sc; xp[4] = x4 * sc; xp[5] = x5 * sc;
  }
  __syncthreads();

  const float bb = biasb[0];
  #pragma unroll
  for (int rep = 0; rep < 2; ++rep) {
    const int qq = w + (rep << 3);
    const float* arow = accL + (qq << 6) * 6;
    float pj0 = 0, pj1 = 0, pj2 = 0, pj3 = 0, pj4 = 0, pj5 = 0;
    for (int f = 0; f < 64; ++f) {
      const float wv = wsiT[(f << 6) + l];
      const float* ap = arow + f * 6;
      pj0 += ap[0] * wv; pj1 += ap[1] * wv; pj2 += ap[2] * wv;
      pj3 += ap[3] * wv; pj4 += ap[4] * wv; pj5 += ap[5] * wv;
    }
    const float s2 = pj0*pj0 + pj1*pj1 + pj2*pj2 + pj3*pj3 + pj4*pj4 + pj5*pj5;
    const float nl = fmaxf(sqrtf(s2) + bb, 0.f);
    const int q = q0 + qq;
    float* o1 = out + (size_t)((n * 256 + q) * 3) * 64 + l;
    float* o2 = o1 + 786432;
    o1[0]   = pj0 * nl;
    o1[64]  = pj1 * nl;
    o1[128] = pj2 * nl;
    o2[0]   = pj3 * nl;
    o2[64]  = pj4 * nl;
    o2[128] = pj5 * nl;
  }
}

extern "C" void kernel_launch(void* const* d_in, const int* in_sizes, int n_in,
                              void* d_out, int out_size, void* d_ws, size_t ws_size,
                              hipStream_t stream) {
  (void)in_sizes; (void)n_in; (void)out_size;
  const size_t ws_needed = (size_t)512 * 6144 * sizeof(float);   // 12.58 MB
  if (ws_size >= ws_needed) {
    tfield_partial<<<dim3(512), dim3(256), 0, stream>>>(
        (const float*)d_in[0], (const float*)d_in[1],
        (const float*)d_in[2], (const float*)d_in[3],
        (const float*)d_in[6], (const float*)d_in[7],
        (const float*)d_in[8], (const float*)d_in[9],
        (float*)d_ws);
    tfield_finish<<<dim3(256), dim3(512), 0, stream>>>(
        (const float*)d_ws, (const float*)d_in[10],
        (const float*)d_in[11], (float*)d_out);
  } else {
    tfield_kernel<<<dim3(256), dim3(512), 0, stream>>>(
        (const float*)d_in[0], (const float*)d_in[1],
        (const float*)d_in[2], (const float*)d_in[3],
        (const float*)d_in[6], (const float*)d_in[7],
        (const float*)d_in[8], (const float*)d_in[9],
        (const float*)d_in[10], (const float*)d_in[11],
        (float*)d_out);
  }
}

// Round 20
// 117.377 us; speedup vs baseline: 1.8305x; 1.0017x over previous
//
#include <hip/hip_runtime.h>
#include <hip/hip_bf16.h>

typedef __attribute__((ext_vector_type(8))) short short8;
typedef __attribute__((ext_vector_type(4))) float f32x4;
typedef __attribute__((ext_vector_type(4))) unsigned int u32x4;

#define MFMA16(A, B, C) __builtin_amdgcn_mfma_f32_16x16x32_bf16(A, B, C, 0, 0, 0)

__device__ __forceinline__ unsigned int pkbf(float lo, float hi) {
  unsigned int ul = (unsigned int)__bfloat16_as_ushort(__float2bfloat16(lo));
  unsigned int uh = (unsigned int)__bfloat16_as_ushort(__float2bfloat16(hi));
  return ul | (uh << 16);
}

union S8U { short8 s; u32x4 u; };
__device__ __forceinline__ short8 mk8(unsigned int a, unsigned int b,
                                      unsigned int c, unsigned int d) {
  S8U t; u32x4 v = {a, b, c, d}; t.u = v; return t.s;
}

constexpr float SU = 0.24430125595146f;   // (1/sqrt2)*sqrt(3/8)/sqrt(pi)
constexpr float SW = 0.34549414947134f;   // (1/sqrt2)*sqrt(3/4)/sqrt(pi)

// MFMA 16x16x32 bf16 layouts (HW-verified, rounds 2-3):
//   A: lane l holds A[row=l&15][k=8*(l>>4)+e];  B: lane l holds B[k=8*(l>>4)+e][col=l&15]
//   C/D: lane l reg v holds D[row=4*(l>>4)+v][col=l&15]

// ============ Kernel A: partial TP — fh-merged + XCD swizzle + setprio ============
// grid 512: WORK id wid = nq*2 + ph; 256 threads (4 waves).
// LADDER: r10 139.8 -> r18 XCD swizzle 124.5 -> r19 fh-merge 117.6.
// This round: re-test T5 setprio on the merged structure (16 MFMA/step now,
// barrier-free phase-diverse waves -> the T5 regime argument is stronger than
// r13's null). Zero register cost; decision rule: keep iff >=4us win.
// REGISTER WINDOW (r5/9/11/12): total arch+acc <= 256 for 2 waves/SIMD;
// current ~240. Known-bad: forced caps spill; W-in-regs/3-deep prefetch cross
// 256; cs-split doubles FETCH; DMA-ring neutral; 12B global_load_lds broken.
__global__ __launch_bounds__(256) void tfield_partial(
    const float* __restrict__ rbf,  const float* __restrict__ uv,
    const float* __restrict__ inp1, const float* __restrict__ inp2,
    const float* __restrict__ W1,   const float* __restrict__ b1,
    const float* __restrict__ W2,   const float* __restrict__ b2,
    float* __restrict__ ws)
{
  // LDS: wfrag 16384 | hbuf 8192 | ibuf 12288 | biasL 512  = 37376 B
  __shared__ __align__(16) unsigned char pool[37376];
  unsigned int* wfrag = (unsigned int*)pool;             // 16 frags x 64 x 16B
  unsigned int* hbuf  = (unsigned int*)(pool + 16384);   // 4 waves x 16 rows x 128B
  float* ibuf  = (float*)(pool + 24576);                 // 4 waves x 2 slots x 384 f32
  float* biasL = (float*)(pool + 36864);                 // 64 b1 + 64 b2
  float* accL  = (float*)pool;                           // epilogue reuse (6144 f32)

  const int tid = threadIdx.x;
  const int l   = tid & 63;
  const int w   = tid >> 6;     // wave 0..3
  const int g   = l >> 4;
  const int qh  = l & 15;

  // XCD-aware remap: bid -> wid ; x = bid&7, k = bid>>3 ; wid = x*64 + k
  const int bid = blockIdx.x;
  const int wid = ((bid & 7) << 6) | (bid >> 3);
  const int nq  = wid >> 1;
  const int ph  = wid & 1;
  const int n   = nq >> 4;
  const int q0  = (nq & 15) << 4;

  // ---- stage 16 W fragments (W1: 0..7, W2: 8..15) + biases ----
  #pragma unroll
  for (int k = 0; k < 4; ++k) {
    const int slot = tid + (k << 8);
    const int fi = slot >> 6;
    const int ll = slot & 63;
    const int gg = ll >> 4;
    const int qq = ll & 15;
    const float* src;
    if (fi < 8) {
      src = W1 + ((fi >> 1) * 16 + qq) * 64 + (fi & 1) * 32 + gg * 8;
    } else {
      const int fj = fi - 8;
      src = W2 + ((fj >> 1) * 16 + qq) * 64 + (fj & 1) * 32 + gg * 8;
    }
    f32x4 x0 = *(const f32x4*)src;
    f32x4 x1 = *(const f32x4*)(src + 4);
    u32x4 vv = {pkbf(x0[0], x0[1]), pkbf(x0[2], x0[3]), pkbf(x1[0], x1[1]), pkbf(x1[2], x1[3])};
    *(u32x4*)(wfrag + ((fi << 6) + ll) * 4) = vv;
  }
  if (tid < 128) biasL[tid] = (tid < 64) ? b1[tid] : b2[tid - 64];
  __syncthreads();

  const float* bL1 = biasL;        // b1[f], f = 16mt+4g+v
  const float* bL2 = biasL + 64;   // b2[f2], f2 = 16mt2+4g+v

  f32x4 accT[4][6];
  #pragma unroll
  for (int a = 0; a < 4; ++a)
    #pragma unroll
    for (int j = 0; j < 6; ++j) accT[a][j] = (f32x4){0.f, 0.f, 0.f, 0.f};

  const size_t nbase = (size_t)n * 256;
  const int pbase = (ph << 7) + w;   // wave w: p = pbase + 4*s, s in [0,32)

  const int sl = (l < 24) ? l : l - 24;
  const float* isrcb = (l < 24) ? inp1 : inp2;
  const int coff = (sl >> 3) * 64 + ((sl & 7) << 2);   // c*64 + 4*(sl&7), f in [0,32)
  const int ldst = (l < 24 ? 0 : 192) + coff;          // LDS offset within slot

  unsigned int* hrow = hbuf + (w << 9) + (qh << 5);
  float* iw = ibuf + w * 768;          // 2 slots x 384 floats
  const int swz = qh & 7;

  // ---- prologue: L1(0) + stage inp(0)/h(0); prefetch step-1 data ----
  f32x4 rn0, rn1, rn2, rn3;
  { const float* rr = rbf + ((nbase + pbase) * 256 + q0 + qh) * 64 + (g << 3);
    rn0 = *(const f32x4*)rr;        rn1 = *(const f32x4*)(rr + 4);
    rn2 = *(const f32x4*)(rr + 32); rn3 = *(const f32x4*)(rr + 36); }
  f32x4 stage_v0 = {0.f,0.f,0.f,0.f}, stage_v1 = {0.f,0.f,0.f,0.f};
  if (l < 48) {
    const float* ip = isrcb + (nbase + pbase) * 192 + coff;
    stage_v0 = *(const f32x4*)ip;
    stage_v1 = *(const f32x4*)(ip + 32);
  }
  float uc0, uc1, uc2, un0, un1, un2;
  { const float* u = uv + ((nbase + pbase) * 256 + q0 + qh) * 3;
    uc0 = u[0]; uc1 = u[1]; uc2 = u[2]; }

  short8 rf0 = mk8(pkbf(rn0[0], rn0[1]), pkbf(rn0[2], rn0[3]), pkbf(rn1[0], rn1[1]), pkbf(rn1[2], rn1[3]));
  short8 rf1 = mk8(pkbf(rn2[0], rn2[1]), pkbf(rn2[2], rn2[3]), pkbf(rn3[0], rn3[1]), pkbf(rn3[2], rn3[3]));
  f32x4 h4[4];
  #pragma unroll
  for (int mt = 0; mt < 4; ++mt) {
    f32x4 c = *(const f32x4*)(bL1 + (mt << 4) + (g << 2));
    short8 a0 = *(const short8*)(wfrag + (((mt << 1) + 0) * 64 + l) * 4);
    short8 a1 = *(const short8*)(wfrag + (((mt << 1) + 1) * 64 + l) * 4);
    c = MFMA16(a0, rf0, c);
    c = MFMA16(a1, rf1, c);
    h4[mt] = c;
  }
  if (l < 48) {                        // slot0 = inp(0)
    *(f32x4*)(iw + ldst) = stage_v0;
    *(f32x4*)(iw + ldst + 32) = stage_v1;
  }
  #pragma unroll
  for (int mt = 0; mt < 4; ++mt) {
    const float e0 = fmaxf(h4[mt][0], 0.f);
    const float e1 = fmaxf(h4[mt][1], 0.f);
    const float e2 = fmaxf(h4[mt][2], 0.f);
    const float e3 = fmaxf(h4[mt][3], 0.f);
    const int base = ((((mt << 1) + (g >> 1)) ^ swz) << 2) + ((g & 1) << 1);
    hrow[base]     = pkbf(e0, e1);
    hrow[base + 1] = pkbf(e2, e3);
  }
  short8 hb0 = *(const short8*)(hrow + (((0 + g) ^ swz) << 2));
  short8 hb1 = *(const short8*)(hrow + (((4 + g) ^ swz) << 2));
  // prefetch step-1 inputs
  { const float* rr = rbf + ((nbase + pbase + 4) * 256 + q0 + qh) * 64 + (g << 3);
    rn0 = *(const f32x4*)rr;        rn1 = *(const f32x4*)(rr + 4);
    rn2 = *(const f32x4*)(rr + 32); rn3 = *(const f32x4*)(rr + 36); }
  if (l < 48) {
    const float* ip = isrcb + (nbase + pbase + 4) * 192 + coff;
    stage_v0 = *(const f32x4*)ip;
    stage_v1 = *(const f32x4*)(ip + 32);
  }
  { const float* u = uv + ((nbase + pbase + 4) * 256 + q0 + qh) * 3;
    un0 = u[0]; un1 = u[1]; un2 = u[2]; }

  for (int s = 0; s < 32; ++s) {
    const int s2 = (s + 2 < 32) ? s + 2 : 31;    // clamped two-ahead prefetch index

    // A: pack rbf(s+1) and start L1 MFMA for step s+1 (shared across all f2)
    rf0 = mk8(pkbf(rn0[0], rn0[1]), pkbf(rn0[2], rn0[3]), pkbf(rn1[0], rn1[1]), pkbf(rn1[2], rn1[3]));
    rf1 = mk8(pkbf(rn2[0], rn2[1]), pkbf(rn2[2], rn2[3]), pkbf(rn3[0], rn3[1]), pkbf(rn3[2], rn3[3]));
    __builtin_amdgcn_s_setprio(1);
    #pragma unroll
    for (int mt = 0; mt < 4; ++mt) {
      f32x4 c = *(const f32x4*)(bL1 + (mt << 4) + (g << 2));
      short8 a0 = *(const short8*)(wfrag + (((mt << 1) + 0) * 64 + l) * 4);
      short8 a1 = *(const short8*)(wfrag + (((mt << 1) + 1) * 64 + l) * 4);
      c = MFMA16(a0, rf0, c);
      c = MFMA16(a1, rf1, c);
      h4[mt] = c;
    }
    __builtin_amdgcn_s_setprio(0);
    // issue rbf(s+2) loads (consumed at top of next iteration)
    { const float* rr = rbf + ((nbase + pbase + (s2 << 2)) * 256 + q0 + qh) * 64 + (g << 3);
      rn0 = *(const f32x4*)rr;        rn1 = *(const f32x4*)(rr + 4);
      rn2 = *(const f32x4*)(rr + 32); rn3 = *(const f32x4*)(rr + 36); }

    // factors for step s; roll uv prefetch
    const float su  = SU * uc0;
    const float sv  = SU * uc1;
    const float swc = SW * uc2;
    uc0 = un0; uc1 = un1; uc2 = un2;
    { const float* u = uv + ((nbase + pbase + (s2 << 2)) * 256 + q0 + qh) * 3;
      un0 = u[0]; un1 = u[1]; un2 = u[2]; }

    // C+D: per f2-quadrant: L2 MFMA then TP accumulate (all 4 quadrants)
    const float* ib = iw + ((s & 1) * 384);
    #pragma unroll
    for (int mt2 = 0; mt2 < 4; ++mt2) {
      f32x4 c = *(const f32x4*)(bL2 + (mt2 << 4) + (g << 2));
      short8 wa0 = *(const short8*)(wfrag + ((8 + (mt2 << 1) + 0) * 64 + l) * 4);
      short8 wa1 = *(const short8*)(wfrag + ((8 + (mt2 << 1) + 1) * 64 + l) * 4);
      __builtin_amdgcn_s_setprio(1);
      c = MFMA16(wa0, hb0, c);
      c = MFMA16(wa1, hb1, c);   // R[f2 = 16mt2+4g+v][q = q0+qh]
      __builtin_amdgcn_s_setprio(0);

      const int fo = (mt2 << 4) + (g << 2);
      const f32x4 A0 = *(const f32x4*)(ib + fo);
      const f32x4 A1 = *(const f32x4*)(ib + fo + 64);
      const f32x4 A2 = *(const f32x4*)(ib + fo + 128);
      const f32x4 B0 = *(const f32x4*)(ib + fo + 192);
      const f32x4 B1 = *(const f32x4*)(ib + fo + 256);
      const f32x4 B2 = *(const f32x4*)(ib + fo + 320);

      const f32x4 t1 = su * A1, t2 = sv * B1;
      const f32x4 t3 = su * B1, t4 = sv * A1;
      const f32x4 g10 = (t1 + t2) - swc * A0;
      const f32x4 g11 = su * (A0 + A2) - sv * (B0 - B2);
      const f32x4 g12 = (t1 - t2) + swc * A2;
      const f32x4 g20 = (t3 - t4) - swc * B0;
      const f32x4 g21 = sv * (A0 - A2) + su * (B0 + B2);
      const f32x4 g22 = (t3 + t4) + swc * B2;
      accT[mt2][0] += c * g10;
      accT[mt2][1] += c * g11;
      accT[mt2][2] += c * g12;
      accT[mt2][3] += c * g20;
      accT[mt2][4] += c * g21;
      accT[mt2][5] += c * g22;
    }

    // E: roll inp staging (write s+1 into the other slot; fetch s+2)
    if (l < 48) {
      float* dst = iw + (((s + 1) & 1) * 384) + ldst;
      *(f32x4*)dst = stage_v0;
      *(f32x4*)(dst + 32) = stage_v1;
      const float* ip = isrcb + (nbase + pbase + (s2 << 2)) * 192 + coff;
      stage_v0 = *(const f32x4*)ip;
      stage_v1 = *(const f32x4*)(ip + 32);
    }

    // E2: relu/pack h(s+1) -> LDS transpose; read hb(s+1) for next iteration
    #pragma unroll
    for (int mt = 0; mt < 4; ++mt) {
      const float e0 = fmaxf(h4[mt][0], 0.f);
      const float e1 = fmaxf(h4[mt][1], 0.f);
      const float e2 = fmaxf(h4[mt][2], 0.f);
      const float e3 = fmaxf(h4[mt][3], 0.f);
      const int base = ((((mt << 1) + (g >> 1)) ^ swz) << 2) + ((g & 1) << 1);
      hrow[base]     = pkbf(e0, e1);
      hrow[base + 1] = pkbf(e2, e3);
    }
    hb0 = *(const short8*)(hrow + (((0 + g) ^ swz) << 2));
    hb1 = *(const short8*)(hrow + (((4 + g) ^ swz) << 2));
  }

  // ---- cross-wave reduce into accL [16 qh][64 f2][6], dump to ws ----
  __syncthreads();
  for (int i = tid; i < 6144; i += 256) accL[i] = 0.f;
  __syncthreads();
  for (int t = 0; t < 4; ++t) {
    if (w == t) {
      #pragma unroll
      for (int mt2 = 0; mt2 < 4; ++mt2)
        #pragma unroll
        for (int v = 0; v < 4; ++v) {
          float* dst = accL + (((qh << 6) + (mt2 << 4) + (g << 2) + v) * 6);
          #pragma unroll
          for (int j = 0; j < 6; ++j) dst[j] += accT[mt2][j][v];
        }
    }
    __syncthreads();
  }
  float* wp = ws + (size_t)wid * 6144;   // partials stored by WORK id
  for (int i = tid; i < 6144; i += 256) wp[i] = accL[i];
}

// ============ Kernel B: combine 2 ph-partials + normalize + project + gate ============
__global__ __launch_bounds__(512) void tfield_finish(
    const float* __restrict__ ws, const float* __restrict__ Wsi,
    const float* __restrict__ biasb, float* __restrict__ out)
{
  __shared__ __align__(16) float accL[6144];   // [16 qh][64 f][6]
  __shared__ __align__(16) float wsiT[4096];   // [64 f][64 g]

  const int tid = threadIdx.x;
  const int l   = tid & 63;
  const int w   = tid >> 6;
  const int nq  = blockIdx.x;
  const int n   = nq >> 4;
  const int q0  = (nq & 15) << 4;

  const float* c0 = ws + (size_t)(nq * 2) * 6144;  // ph0
  const float* c1 = c0 + 6144;                     // ph1
  for (int i = tid; i < 6144; i += 512) accL[i] = c0[i] + c1[i];
  #pragma unroll
  for (int k = 0; k < 8; ++k) {
    const int f = (w << 3) + k;
    wsiT[(f << 6) + l] = Wsi[(l << 6) + f];
  }
  __syncthreads();

  #pragma unroll
  for (int rep = 0; rep < 2; ++rep) {
    const int qq = w + (rep << 3);
    float* xp = accL + ((qq << 6) + l) * 6;
    const float x0 = xp[0], x1 = xp[1], x2 = xp[2], x3 = xp[3], x4 = xp[4], x5 = xp[5];
    const float nrm = sqrtf(x0*x0 + x1*x1 + x2*x2 + x3*x3 + x4*x4 + x5*x5);
    const float sc = 1.f / (nrm + 1e-9f);
    xp[0] = x0 * sc; xp[1] = x1 * sc; xp[2] = x2 * sc;
    xp[3] = x3 * sc; xp[4] = x4 * sc; xp[5] = x5 * sc;
  }
  __syncthreads();

  const float bb = biasb[0];
  #pragma unroll
  for (int rep = 0; rep < 2; ++rep) {
    const int qq = w + (rep << 3);
    const float* arow = accL + (qq << 6) * 6;
    float pj0 = 0, pj1 = 0, pj2 = 0, pj3 = 0, pj4 = 0, pj5 = 0;
    for (int f = 0; f < 64; ++f) {
      const float wv = wsiT[(f << 6) + l];
      const float* ap = arow + f * 6;
      pj0 += ap[0] * wv; pj1 += ap[1] * wv; pj2 += ap[2] * wv;
      pj3 += ap[3] * wv; pj4 += ap[4] * wv; pj5 += ap[5] * wv;
    }
    const float s2 = pj0*pj0 + pj1*pj1 + pj2*pj2 + pj3*pj3 + pj4*pj4 + pj5*pj5;
    const float nl = fmaxf(sqrtf(s2) + bb, 0.f);
    const int q = q0 + qq;
    float* o1 = out + (size_t)((n * 256 + q) * 3) * 64 + l;   // out1[n,q,c,g]
    float* o2 = o1 + 786432;                                   // out2
    o1[0]   = pj0 * nl;
    o1[64]  = pj1 * nl;
    o1[128] = pj2 * nl;
    o2[0]   = pj3 * nl;
    o2[64]  = pj4 * nl;
    o2[128] = pj5 * nl;
  }
}

// ============ Fallback: round-4 monolithic kernel (used if ws too small) ============
__global__ __launch_bounds__(512) void tfield_kernel(
    const float* __restrict__ rbf,  const float* __restrict__ uv,
    const float* __restrict__ inp1, const float* __restrict__ inp2,
    const float* __restrict__ W1,   const float* __restrict__ b1,
    const float* __restrict__ W2,   const float* __restrict__ b2,
    const float* __restrict__ Wsi,  const float* __restrict__ biasb,
    float* __restrict__ out)
{
  __shared__ __align__(16) unsigned char pool[40960];
  unsigned int* wfrag = (unsigned int*)pool;
  unsigned int* hbuf  = (unsigned int*)(pool + 16384);
  float* accL = (float*)pool;
  float* wsiT = (float*)(pool + 24576);

  const int tid = threadIdx.x;
  const int l   = tid & 63;
  const int w   = tid >> 6;
  const int g   = l >> 4;
  const int qh  = l & 15;
  const int n   = blockIdx.x >> 4;
  const int q0  = (blockIdx.x & 15) << 4;

  {
    const int row = ((w >> 1) << 4) + qh;
    const int kb  = ((w & 1) << 5) + (g << 3);
    const float* s1 = W1 + row * 64 + kb;
    f32x4 x0 = *(const f32x4*)s1;
    f32x4 x1 = *(const f32x4*)(s1 + 4);
    u32x4 v1 = {pkbf(x0[0], x0[1]), pkbf(x0[2], x0[3]), pkbf(x1[0], x1[1]), pkbf(x1[2], x1[3])};
    *(u32x4*)(wfrag + ((w << 6) + l) * 4) = v1;
    const float* s2 = W2 + row * 64 + kb;
    x0 = *(const f32x4*)s2;
    x1 = *(const f32x4*)(s2 + 4);
    u32x4 v2 = {pkbf(x0[0], x0[1]), pkbf(x0[2], x0[3]), pkbf(x1[0], x1[1]), pkbf(x1[2], x1[3])};
    *(u32x4*)(wfrag + (((8 + w) << 6) + l) * 4) = v2;
  }
  __syncthreads();

  float accT[4][4][6];
  #pragma unroll
  for (int a = 0; a < 4; ++a)
    #pragma unroll
    for (int b = 0; b < 4; ++b)
      #pragma unroll
      for (int j = 0; j < 6; ++j) accT[a][b][j] = 0.f;

  const size_t nbase = (size_t)n * 256;
  const float* rr0 = rbf + ((nbase + w) * 256 + q0 + qh) * 64 + (g << 3);
  f32x4 nx0 = *(const f32x4*)(rr0);
  f32x4 nx1 = *(const f32x4*)(rr0 + 4);
  f32x4 nx2 = *(const f32x4*)(rr0 + 32);
  f32x4 nx3 = *(const f32x4*)(rr0 + 36);

  unsigned int* hrow = hbuf + ((w << 4) + qh) * 32;
  const int swz = qh & 7;

  for (int s = 0; s < 32; ++s) {
    const int p = (s << 3) + w;
    f32x4 r0 = nx0, r1 = nx1, r2 = nx2, r3 = nx3;
    {
      const int pn = (s < 31) ? p + 8 : p;
      const float* rr = rbf + ((nbase + pn) * 256 + q0 + qh) * 64 + (g << 3);
      nx0 = *(const f32x4*)(rr);
      nx1 = *(const f32x4*)(rr + 4);
      nx2 = *(const f32x4*)(rr + 32);
      nx3 = *(const f32x4*)(rr + 36);
    }
    const float* uvp = uv + ((nbase + p) * 256 + q0 + qh) * 3;
    const float su = SU * uvp[0];
    const float sv = SU * uvp[1];
    const float swc = SW * uvp[2];

    const short8 rf0 = mk8(pkbf(r0[0], r0[1]), pkbf(r0[2], r0[3]), pkbf(r1[0], r1[1]), pkbf(r1[2], r1[3]));
    const short8 rf1 = mk8(pkbf(r2[0], r2[1]), pkbf(r2[2], r2[3]), pkbf(r3[0], r3[1]), pkbf(r3[2], r3[3]));

    f32x4 h4[4];
    #pragma unroll
    for (int mt = 0; mt < 4; ++mt) {
      f32x4 c = *(const f32x4*)(b1 + (mt << 4) + (g << 2));
      short8 a0 = *(const short8*)(wfrag + (((mt << 1) + 0) * 64 + l) * 4);
      short8 a1 = *(const short8*)(wfrag + (((mt << 1) + 1) * 64 + l) * 4);
      c = MFMA16(a0, rf0, c);
      c = MFMA16(a1, rf1, c);
      h4[mt] = c;
    }
    #pragma unroll
    for (int mt = 0; mt < 4; ++mt) {
      const float e0 = fmaxf(h4[mt][0], 0.f);
      const float e1 = fmaxf(h4[mt][1], 0.f);
      const float e2 = fmaxf(h4[mt][2], 0.f);
      const float e3 = fmaxf(h4[mt][3], 0.f);
      const int base = ((((mt << 1) + (g >> 1)) ^ swz) << 2) + ((g & 1) << 1);
      hrow[base]     = pkbf(e0, e1);
      hrow[base + 1] = pkbf(e2, e3);
    }
    const short8 hb0 = *(const short8*)(hrow + (((0 + g) ^ swz) << 2));
    const short8 hb1 = *(const short8*)(hrow + (((4 + g) ^ swz) << 2));

    const float* i1p = inp1 + (nbase + p) * 192 + (g << 2);
    const float* i2p = inp2 + (nbase + p) * 192 + (g << 2);

    #pragma unroll
    for (int mt2 = 0; mt2 < 4; ++mt2) {
      f32x4 c = *(const f32x4*)(b2 + (mt2 << 4) + (g << 2));
      short8 wa0 = *(const short8*)(wfrag + ((8 + (mt2 << 1) + 0) * 64 + l) * 4);
      short8 wa1 = *(const short8*)(wfrag + ((8 + (mt2 << 1) + 1) * 64 + l) * 4);
      c = MFMA16(wa0, hb0, c);
      c = MFMA16(wa1, hb1, c);

      const int fo = mt2 << 4;
      const f32x4 A0 = *(const f32x4*)(i1p + fo);
      const f32x4 A1 = *(const f32x4*)(i1p + fo + 64);
      const f32x4 A2 = *(const f32x4*)(i1p + fo + 128);
      const f32x4 B0 = *(const f32x4*)(i2p + fo);
      const f32x4 B1 = *(const f32x4*)(i2p + fo + 64);
      const f32x4 B2 = *(const f32x4*)(i2p + fo + 128);
      const f32x4 a02p = A0 + A2, a02m = A0 - A2;
      const f32x4 b02p = B0 + B2, b02m = B0 - B2;

      #pragma unroll
      for (int v = 0; v < 4; ++v) {
        const float R = c[v];
        const float pua1 = su * A1[v], pvb1 = sv * B1[v];
        const float pub1 = su * B1[v], pva1 = sv * A1[v];
        const float g10 = pua1 - swc * A0[v] + pvb1;
        const float g11 = su * a02p[v] - sv * b02m[v];
        const float g12 = swc * A2[v] + pua1 - pvb1;
        const float g20 = pub1 - swc * B0[v] - pva1;
        const float g21 = sv * a02m[v] + su * b02p[v];
        const float g22 = swc * B2[v] + pub1 + pva1;
        accT[mt2][v][0] += R * g10;
        accT[mt2][v][1] += R * g11;
        accT[mt2][v][2] += R * g12;
        accT[mt2][v][3] += R * g20;
        accT[mt2][v][4] += R * g21;
        accT[mt2][v][5] += R * g22;
      }
    }
  }

  __syncthreads();
  for (int i = tid; i < 16 * 64 * 6; i += 512) accL[i] = 0.f;
  #pragma unroll
  for (int k = 0; k < 8; ++k) {
    const int f = (w << 3) + k;
    wsiT[(f << 6) + l] = Wsi[(l << 6) + f];
  }
  __syncthreads();

  for (int t = 0; t < 8; ++t) {
    if (w == t) {
      #pragma unroll
      for (int mt2 = 0; mt2 < 4; ++mt2)
        #pragma unroll
        for (int v = 0; v < 4; ++v) {
          float* dst = accL + (((qh << 6) + (mt2 << 4) + (g << 2) + v) * 6);
          #pragma unroll
          for (int j = 0; j < 6; ++j) dst[j] += accT[mt2][v][j];
        }
    }
    __syncthreads();
  }

  #pragma unroll
  for (int rep = 0; rep < 2; ++rep) {
    const int qq = w + (rep << 3);
    float* xp = accL + ((qq << 6) + l) * 6;
    const float x0 = xp[0], x1 = xp[1], x2 = xp[2], x3 = xp[3], x4 = xp[4], x5 = xp[5];
    const float nrm = sqrtf(x0*x0 + x1*x1 + x2*x2 + x3*x3 + x4*x4 + x5*x5);
    const float sc = 1.f / (nrm + 1e-9f);
    xp[0] = x0 * sc; xp[1] = x1 * sc; xp[2] = x2 * sc;
    xp[3] = x3 * sc; xp[4] = x4 * sc; xp[5] = x5 * sc;
  }
  __syncthreads();

  const float bb = biasb[0];
  #pragma unroll
  for (int rep = 0; rep < 2; ++rep) {
    const int qq = w + (rep << 3);
    const float* arow = accL + (qq << 6) * 6;
    float pj0 = 0, pj1 = 0, pj2 = 0, pj3 = 0, pj4 = 0, pj5 = 0;
    for (int f = 0; f < 64; ++f) {
      const float wv = wsiT[(f << 6) + l];
      const float* ap = arow + f * 6;
      pj0 += ap[0] * wv; pj1 += ap[1] * wv; pj2 += ap[2] * wv;
      pj3 += ap[3] * wv; pj4 += ap[4] * wv; pj5 += ap[5] * wv;
    }
    const float s2 = pj0*pj0 + pj1*pj1 + pj2*pj2 + pj3*pj3 + pj4*pj4 + pj5*pj5;
    const float nl = fmaxf(sqrtf(s2) + bb, 0.f);
    const int q = q0 + qq;
    float* o1 = out + (size_t)((n * 256 + q) * 3) * 64 + l;
    float* o2 = o1 + 786432;
    o1[0]   = pj0 * nl;
    o1[64]  = pj1 * nl;
    o1[128] = pj2 * nl;
    o2[0]   = pj3 * nl;
    o2[64]  = pj4 * nl;
    o2[128] = pj5 * nl;
  }
}

extern "C" void kernel_launch(void* const* d_in, const int* in_sizes, int n_in,
                              void* d_out, int out_size, void* d_ws, size_t ws_size,
                              hipStream_t stream) {
  (void)in_sizes; (void)n_in; (void)out_size;
  const size_t ws_needed = (size_t)512 * 6144 * sizeof(float);   // 12.58 MB
  if (ws_size >= ws_needed) {
    tfield_partial<<<dim3(512), dim3(256), 0, stream>>>(
        (const float*)d_in[0], (const float*)d_in[1],
        (const float*)d_in[2], (const float*)d_in[3],
        (const float*)d_in[6], (const float*)d_in[7],
        (const float*)d_in[8], (const float*)d_in[9],
        (float*)d_ws);
    tfield_finish<<<dim3(256), dim3(512), 0, stream>>>(
        (const float*)d_ws, (const float*)d_in[10],
        (const float*)d_in[11], (float*)d_out);
  } else {
    tfield_kernel<<<dim3(256), dim3(512), 0, stream>>>(
        (const float*)d_in[0], (const float*)d_in[1],
        (const float*)d_in[2], (const float*)d_in[3],
        (const float*)d_in[6], (const float*)d_in[7],
        (const float*)d_in[8], (const float*)d_in[9],
        (const float*)d_in[10], (const float*)d_in[11],
        (float*)d_out);
  }
}

// Round 21
// 116.989 us; speedup vs baseline: 1.8365x; 1.0033x over previous
//
#include <hip/hip_runtime.h>
#include <hip/hip_bf16.h>

typedef __attribute__((ext_vector_type(8))) short short8;
typedef __attribute__((ext_vector_type(4))) float f32x4;
typedef __attribute__((ext_vector_type(4))) unsigned int u32x4;

#define MFMA16(A, B, C) __builtin_amdgcn_mfma_f32_16x16x32_bf16(A, B, C, 0, 0, 0)

__device__ __forceinline__ unsigned int pkbf(float lo, float hi) {
  unsigned int ul = (unsigned int)__bfloat16_as_ushort(__float2bfloat16(lo));
  unsigned int uh = (unsigned int)__bfloat16_as_ushort(__float2bfloat16(hi));
  return ul | (uh << 16);
}

union S8U { short8 s; u32x4 u; };
__device__ __forceinline__ short8 mk8(unsigned int a, unsigned int b,
                                      unsigned int c, unsigned int d) {
  S8U t; u32x4 v = {a, b, c, d}; t.u = v; return t.s;
}

constexpr float SU = 0.24430125595146f;   // (1/sqrt2)*sqrt(3/8)/sqrt(pi)
constexpr float SW = 0.34549414947134f;   // (1/sqrt2)*sqrt(3/4)/sqrt(pi)

// MFMA 16x16x32 bf16 layouts (HW-verified, rounds 2-3):
//   A: lane l holds A[row=l&15][k=8*(l>>4)+e];  B: lane l holds B[k=8*(l>>4)+e][col=l&15]
//   C/D: lane l reg v holds D[row=4*(l>>4)+v][col=l&15]

// ============ Kernel A: partial TP — FINAL (fh-merged + XCD swizzle) ============
// grid 512: WORK id wid = nq*2 + ph; 256 threads (4 waves).
// LADDER: r4 200us -> r10 pipeline+packed 139.8 -> r18 XCD swizzle 124.5 ->
// r19 fh-merge 117.6 (final). Probed-and-retired levers:
//  * REGISTER WINDOW: total arch+acc <= 256 for 2 waves/SIMD (~240 here).
//    Forced caps spill (r5/r9, 2.6-3.2x); extra consumers halve occ (r11/12).
//  * setprio: null on both structures (r13, r20). DMA-ring depth-2: neutral
//    (r15) -> load latency already covered; stall is mixed LDS/VALU/dep.
//  * cs-split: FETCH x2 (rbf 268MB > 256MB L3), 1.6x slower (r16).
//  * 12B global_load_lds: broken (r14 correctness failure). 16B verified.
__global__ __launch_bounds__(256) void tfield_partial(
    const float* __restrict__ rbf,  const float* __restrict__ uv,
    const float* __restrict__ inp1, const float* __restrict__ inp2,
    const float* __restrict__ W1,   const float* __restrict__ b1,
    const float* __restrict__ W2,   const float* __restrict__ b2,
    float* __restrict__ ws)
{
  // LDS: wfrag 16384 | hbuf 8192 | ibuf 12288 | biasL 512  = 37376 B
  __shared__ __align__(16) unsigned char pool[37376];
  unsigned int* wfrag = (unsigned int*)pool;             // 16 frags x 64 x 16B
  unsigned int* hbuf  = (unsigned int*)(pool + 16384);   // 4 waves x 16 rows x 128B
  float* ibuf  = (float*)(pool + 24576);                 // 4 waves x 2 slots x 384 f32
  float* biasL = (float*)(pool + 36864);                 // 64 b1 + 64 b2
  float* accL  = (float*)pool;                           // epilogue reuse (6144 f32)

  const int tid = threadIdx.x;
  const int l   = tid & 63;
  const int w   = tid >> 6;     // wave 0..3
  const int g   = l >> 4;
  const int qh  = l & 15;

  // XCD-aware remap: bid -> wid ; x = bid&7, k = bid>>3 ; wid = x*64 + k
  const int bid = blockIdx.x;
  const int wid = ((bid & 7) << 6) | (bid >> 3);
  const int nq  = wid >> 1;
  const int ph  = wid & 1;
  const int n   = nq >> 4;
  const int q0  = (nq & 15) << 4;

  // ---- stage 16 W fragments (W1: 0..7, W2: 8..15) + biases ----
  #pragma unroll
  for (int k = 0; k < 4; ++k) {
    const int slot = tid + (k << 8);
    const int fi = slot >> 6;
    const int ll = slot & 63;
    const int gg = ll >> 4;
    const int qq = ll & 15;
    const float* src;
    if (fi < 8) {
      src = W1 + ((fi >> 1) * 16 + qq) * 64 + (fi & 1) * 32 + gg * 8;
    } else {
      const int fj = fi - 8;
      src = W2 + ((fj >> 1) * 16 + qq) * 64 + (fj & 1) * 32 + gg * 8;
    }
    f32x4 x0 = *(const f32x4*)src;
    f32x4 x1 = *(const f32x4*)(src + 4);
    u32x4 vv = {pkbf(x0[0], x0[1]), pkbf(x0[2], x0[3]), pkbf(x1[0], x1[1]), pkbf(x1[2], x1[3])};
    *(u32x4*)(wfrag + ((fi << 6) + ll) * 4) = vv;
  }
  if (tid < 128) biasL[tid] = (tid < 64) ? b1[tid] : b2[tid - 64];
  __syncthreads();

  const float* bL1 = biasL;        // b1[f], f = 16mt+4g+v
  const float* bL2 = biasL + 64;   // b2[f2], f2 = 16mt2+4g+v

  f32x4 accT[4][6];
  #pragma unroll
  for (int a = 0; a < 4; ++a)
    #pragma unroll
    for (int j = 0; j < 6; ++j) accT[a][j] = (f32x4){0.f, 0.f, 0.f, 0.f};

  const size_t nbase = (size_t)n * 256;
  const int pbase = (ph << 7) + w;   // wave w: p = pbase + 4*s, s in [0,32)

  const int sl = (l < 24) ? l : l - 24;
  const float* isrcb = (l < 24) ? inp1 : inp2;
  const int coff = (sl >> 3) * 64 + ((sl & 7) << 2);   // c*64 + 4*(sl&7), f in [0,32)
  const int ldst = (l < 24 ? 0 : 192) + coff;          // LDS offset within slot

  unsigned int* hrow = hbuf + (w << 9) + (qh << 5);
  float* iw = ibuf + w * 768;          // 2 slots x 384 floats
  const int swz = qh & 7;

  // ---- prologue: L1(0) + stage inp(0)/h(0); prefetch step-1 data ----
  f32x4 rn0, rn1, rn2, rn3;
  { const float* rr = rbf + ((nbase + pbase) * 256 + q0 + qh) * 64 + (g << 3);
    rn0 = *(const f32x4*)rr;        rn1 = *(const f32x4*)(rr + 4);
    rn2 = *(const f32x4*)(rr + 32); rn3 = *(const f32x4*)(rr + 36); }
  f32x4 stage_v0 = {0.f,0.f,0.f,0.f}, stage_v1 = {0.f,0.f,0.f,0.f};
  if (l < 48) {
    const float* ip = isrcb + (nbase + pbase) * 192 + coff;
    stage_v0 = *(const f32x4*)ip;
    stage_v1 = *(const f32x4*)(ip + 32);
  }
  float uc0, uc1, uc2, un0, un1, un2;
  { const float* u = uv + ((nbase + pbase) * 256 + q0 + qh) * 3;
    uc0 = u[0]; uc1 = u[1]; uc2 = u[2]; }

  short8 rf0 = mk8(pkbf(rn0[0], rn0[1]), pkbf(rn0[2], rn0[3]), pkbf(rn1[0], rn1[1]), pkbf(rn1[2], rn1[3]));
  short8 rf1 = mk8(pkbf(rn2[0], rn2[1]), pkbf(rn2[2], rn2[3]), pkbf(rn3[0], rn3[1]), pkbf(rn3[2], rn3[3]));
  f32x4 h4[4];
  #pragma unroll
  for (int mt = 0; mt < 4; ++mt) {
    f32x4 c = *(const f32x4*)(bL1 + (mt << 4) + (g << 2));
    short8 a0 = *(const short8*)(wfrag + (((mt << 1) + 0) * 64 + l) * 4);
    short8 a1 = *(const short8*)(wfrag + (((mt << 1) + 1) * 64 + l) * 4);
    c = MFMA16(a0, rf0, c);
    c = MFMA16(a1, rf1, c);
    h4[mt] = c;
  }
  if (l < 48) {                        // slot0 = inp(0)
    *(f32x4*)(iw + ldst) = stage_v0;
    *(f32x4*)(iw + ldst + 32) = stage_v1;
  }
  #pragma unroll
  for (int mt = 0; mt < 4; ++mt) {
    const float e0 = fmaxf(h4[mt][0], 0.f);
    const float e1 = fmaxf(h4[mt][1], 0.f);
    const float e2 = fmaxf(h4[mt][2], 0.f);
    const float e3 = fmaxf(h4[mt][3], 0.f);
    const int base = ((((mt << 1) + (g >> 1)) ^ swz) << 2) + ((g & 1) << 1);
    hrow[base]     = pkbf(e0, e1);
    hrow[base + 1] = pkbf(e2, e3);
  }
  short8 hb0 = *(const short8*)(hrow + (((0 + g) ^ swz) << 2));
  short8 hb1 = *(const short8*)(hrow + (((4 + g) ^ swz) << 2));
  // prefetch step-1 inputs
  { const float* rr = rbf + ((nbase + pbase + 4) * 256 + q0 + qh) * 64 + (g << 3);
    rn0 = *(const f32x4*)rr;        rn1 = *(const f32x4*)(rr + 4);
    rn2 = *(const f32x4*)(rr + 32); rn3 = *(const f32x4*)(rr + 36); }
  if (l < 48) {
    const float* ip = isrcb + (nbase + pbase + 4) * 192 + coff;
    stage_v0 = *(const f32x4*)ip;
    stage_v1 = *(const f32x4*)(ip + 32);
  }
  { const float* u = uv + ((nbase + pbase + 4) * 256 + q0 + qh) * 3;
    un0 = u[0]; un1 = u[1]; un2 = u[2]; }

  for (int s = 0; s < 32; ++s) {
    const int s2 = (s + 2 < 32) ? s + 2 : 31;    // clamped two-ahead prefetch index

    // A: pack rbf(s+1) and start L1 MFMA for step s+1 (shared across all f2)
    rf0 = mk8(pkbf(rn0[0], rn0[1]), pkbf(rn0[2], rn0[3]), pkbf(rn1[0], rn1[1]), pkbf(rn1[2], rn1[3]));
    rf1 = mk8(pkbf(rn2[0], rn2[1]), pkbf(rn2[2], rn2[3]), pkbf(rn3[0], rn3[1]), pkbf(rn3[2], rn3[3]));
    #pragma unroll
    for (int mt = 0; mt < 4; ++mt) {
      f32x4 c = *(const f32x4*)(bL1 + (mt << 4) + (g << 2));
      short8 a0 = *(const short8*)(wfrag + (((mt << 1) + 0) * 64 + l) * 4);
      short8 a1 = *(const short8*)(wfrag + (((mt << 1) + 1) * 64 + l) * 4);
      c = MFMA16(a0, rf0, c);
      c = MFMA16(a1, rf1, c);
      h4[mt] = c;
    }
    // issue rbf(s+2) loads (consumed at top of next iteration)
    { const float* rr = rbf + ((nbase + pbase + (s2 << 2)) * 256 + q0 + qh) * 64 + (g << 3);
      rn0 = *(const f32x4*)rr;        rn1 = *(const f32x4*)(rr + 4);
      rn2 = *(const f32x4*)(rr + 32); rn3 = *(const f32x4*)(rr + 36); }

    // factors for step s; roll uv prefetch
    const float su  = SU * uc0;
    const float sv  = SU * uc1;
    const float swc = SW * uc2;
    uc0 = un0; uc1 = un1; uc2 = un2;
    { const float* u = uv + ((nbase + pbase + (s2 << 2)) * 256 + q0 + qh) * 3;
      un0 = u[0]; un1 = u[1]; un2 = u[2]; }

    // C+D: per f2-quadrant: L2 MFMA then TP accumulate (all 4 quadrants)
    const float* ib = iw + ((s & 1) * 384);
    #pragma unroll
    for (int mt2 = 0; mt2 < 4; ++mt2) {
      f32x4 c = *(const f32x4*)(bL2 + (mt2 << 4) + (g << 2));
      short8 wa0 = *(const short8*)(wfrag + ((8 + (mt2 << 1) + 0) * 64 + l) * 4);
      short8 wa1 = *(const short8*)(wfrag + ((8 + (mt2 << 1) + 1) * 64 + l) * 4);
      c = MFMA16(wa0, hb0, c);
      c = MFMA16(wa1, hb1, c);   // R[f2 = 16mt2+4g+v][q = q0+qh]

      const int fo = (mt2 << 4) + (g << 2);
      const f32x4 A0 = *(const f32x4*)(ib + fo);
      const f32x4 A1 = *(const f32x4*)(ib + fo + 64);
      const f32x4 A2 = *(const f32x4*)(ib + fo + 128);
      const f32x4 B0 = *(const f32x4*)(ib + fo + 192);
      const f32x4 B1 = *(const f32x4*)(ib + fo + 256);
      const f32x4 B2 = *(const f32x4*)(ib + fo + 320);

      const f32x4 t1 = su * A1, t2 = sv * B1;
      const f32x4 t3 = su * B1, t4 = sv * A1;
      const f32x4 g10 = (t1 + t2) - swc * A0;
      const f32x4 g11 = su * (A0 + A2) - sv * (B0 - B2);
      const f32x4 g12 = (t1 - t2) + swc * A2;
      const f32x4 g20 = (t3 - t4) - swc * B0;
      const f32x4 g21 = sv * (A0 - A2) + su * (B0 + B2);
      const f32x4 g22 = (t3 + t4) + swc * B2;
      accT[mt2][0] += c * g10;
      accT[mt2][1] += c * g11;
      accT[mt2][2] += c * g12;
      accT[mt2][3] += c * g20;
      accT[mt2][4] += c * g21;
      accT[mt2][5] += c * g22;
    }

    // E: roll inp staging (write s+1 into the other slot; fetch s+2)
    if (l < 48) {
      float* dst = iw + (((s + 1) & 1) * 384) + ldst;
      *(f32x4*)dst = stage_v0;
      *(f32x4*)(dst + 32) = stage_v1;
      const float* ip = isrcb + (nbase + pbase + (s2 << 2)) * 192 + coff;
      stage_v0 = *(const f32x4*)ip;
      stage_v1 = *(const f32x4*)(ip + 32);
    }

    // E2: relu/pack h(s+1) -> LDS transpose; read hb(s+1) for next iteration
    #pragma unroll
    for (int mt = 0; mt < 4; ++mt) {
      const float e0 = fmaxf(h4[mt][0], 0.f);
      const float e1 = fmaxf(h4[mt][1], 0.f);
      const float e2 = fmaxf(h4[mt][2], 0.f);
      const float e3 = fmaxf(h4[mt][3], 0.f);
      const int base = ((((mt << 1) + (g >> 1)) ^ swz) << 2) + ((g & 1) << 1);
      hrow[base]     = pkbf(e0, e1);
      hrow[base + 1] = pkbf(e2, e3);
    }
    hb0 = *(const short8*)(hrow + (((0 + g) ^ swz) << 2));
    hb1 = *(const short8*)(hrow + (((4 + g) ^ swz) << 2));
  }

  // ---- cross-wave reduce into accL [16 qh][64 f2][6], dump to ws ----
  __syncthreads();
  for (int i = tid; i < 6144; i += 256) accL[i] = 0.f;
  __syncthreads();
  for (int t = 0; t < 4; ++t) {
    if (w == t) {
      #pragma unroll
      for (int mt2 = 0; mt2 < 4; ++mt2)
        #pragma unroll
        for (int v = 0; v < 4; ++v) {
          float* dst = accL + (((qh << 6) + (mt2 << 4) + (g << 2) + v) * 6);
          #pragma unroll
          for (int j = 0; j < 6; ++j) dst[j] += accT[mt2][j][v];
        }
    }
    __syncthreads();
  }
  float* wp = ws + (size_t)wid * 6144;   // partials stored by WORK id
  for (int i = tid; i < 6144; i += 256) wp[i] = accL[i];
}

// ============ Kernel B: combine 2 ph-partials + normalize + project + gate ============
__global__ __launch_bounds__(512) void tfield_finish(
    const float* __restrict__ ws, const float* __restrict__ Wsi,
    const float* __restrict__ biasb, float* __restrict__ out)
{
  __shared__ __align__(16) float accL[6144];   // [16 qh][64 f][6]
  __shared__ __align__(16) float wsiT[4096];   // [64 f][64 g]

  const int tid = threadIdx.x;
  const int l   = tid & 63;
  const int w   = tid >> 6;
  const int nq  = blockIdx.x;
  const int n   = nq >> 4;
  const int q0  = (nq & 15) << 4;

  const float* c0 = ws + (size_t)(nq * 2) * 6144;  // ph0
  const float* c1 = c0 + 6144;                     // ph1
  for (int i = tid; i < 6144; i += 512) accL[i] = c0[i] + c1[i];
  #pragma unroll
  for (int k = 0; k < 8; ++k) {
    const int f = (w << 3) + k;
    wsiT[(f << 6) + l] = Wsi[(l << 6) + f];
  }
  __syncthreads();

  #pragma unroll
  for (int rep = 0; rep < 2; ++rep) {
    const int qq = w + (rep << 3);
    float* xp = accL + ((qq << 6) + l) * 6;
    const float x0 = xp[0], x1 = xp[1], x2 = xp[2], x3 = xp[3], x4 = xp[4], x5 = xp[5];
    const float nrm = sqrtf(x0*x0 + x1*x1 + x2*x2 + x3*x3 + x4*x4 + x5*x5);
    const float sc = 1.f / (nrm + 1e-9f);
    xp[0] = x0 * sc; xp[1] = x1 * sc; xp[2] = x2 * sc;
    xp[3] = x3 * sc; xp[4] = x4 * sc; xp[5] = x5 * sc;
  }
  __syncthreads();

  const float bb = biasb[0];
  #pragma unroll
  for (int rep = 0; rep < 2; ++rep) {
    const int qq = w + (rep << 3);
    const float* arow = accL + (qq << 6) * 6;
    float pj0 = 0, pj1 = 0, pj2 = 0, pj3 = 0, pj4 = 0, pj5 = 0;
    for (int f = 0; f < 64; ++f) {
      const float wv = wsiT[(f << 6) + l];
      const float* ap = arow + f * 6;
      pj0 += ap[0] * wv; pj1 += ap[1] * wv; pj2 += ap[2] * wv;
      pj3 += ap[3] * wv; pj4 += ap[4] * wv; pj5 += ap[5] * wv;
    }
    const float s2 = pj0*pj0 + pj1*pj1 + pj2*pj2 + pj3*pj3 + pj4*pj4 + pj5*pj5;
    const float nl = fmaxf(sqrtf(s2) + bb, 0.f);
    const int q = q0 + qq;
    float* o1 = out + (size_t)((n * 256 + q) * 3) * 64 + l;   // out1[n,q,c,g]
    float* o2 = o1 + 786432;                                   // out2
    o1[0]   = pj0 * nl;
    o1[64]  = pj1 * nl;
    o1[128] = pj2 * nl;
    o2[0]   = pj3 * nl;
    o2[64]  = pj4 * nl;
    o2[128] = pj5 * nl;
  }
}

// ============ Fallback: round-4 monolithic kernel (used if ws too small) ============
__global__ __launch_bounds__(512) void tfield_kernel(
    const float* __restrict__ rbf,  const float* __restrict__ uv,
    const float* __restrict__ inp1, const float* __restrict__ inp2,
    const float* __restrict__ W1,   const float* __restrict__ b1,
    const float* __restrict__ W2,   const float* __restrict__ b2,
    const float* __restrict__ Wsi,  const float* __restrict__ biasb,
    float* __restrict__ out)
{
  __shared__ __align__(16) unsigned char pool[40960];
  unsigned int* wfrag = (unsigned int*)pool;
  unsigned int* hbuf  = (unsigned int*)(pool + 16384);
  float* accL = (float*)pool;
  float* wsiT = (float*)(pool + 24576);

  const int tid = threadIdx.x;
  const int l   = tid & 63;
  const int w   = tid >> 6;
  const int g   = l >> 4;
  const int qh  = l & 15;
  const int n   = blockIdx.x >> 4;
  const int q0  = (blockIdx.x & 15) << 4;

  {
    const int row = ((w >> 1) << 4) + qh;
    const int kb  = ((w & 1) << 5) + (g << 3);
    const float* s1 = W1 + row * 64 + kb;
    f32x4 x0 = *(const f32x4*)s1;
    f32x4 x1 = *(const f32x4*)(s1 + 4);
    u32x4 v1 = {pkbf(x0[0], x0[1]), pkbf(x0[2], x0[3]), pkbf(x1[0], x1[1]), pkbf(x1[2], x1[3])};
    *(u32x4*)(wfrag + ((w << 6) + l) * 4) = v1;
    const float* s2 = W2 + row * 64 + kb;
    x0 = *(const f32x4*)s2;
    x1 = *(const f32x4*)(s2 + 4);
    u32x4 v2 = {pkbf(x0[0], x0[1]), pkbf(x0[2], x0[3]), pkbf(x1[0], x1[1]), pkbf(x1[2], x1[3])};
    *(u32x4*)(wfrag + (((8 + w) << 6) + l) * 4) = v2;
  }
  __syncthreads();

  float accT[4][4][6];
  #pragma unroll
  for (int a = 0; a < 4; ++a)
    #pragma unroll
    for (int b = 0; b < 4; ++b)
      #pragma unroll
      for (int j = 0; j < 6; ++j) accT[a][b][j] = 0.f;

  const size_t nbase = (size_t)n * 256;
  const float* rr0 = rbf + ((nbase + w) * 256 + q0 + qh) * 64 + (g << 3);
  f32x4 nx0 = *(const f32x4*)(rr0);
  f32x4 nx1 = *(const f32x4*)(rr0 + 4);
  f32x4 nx2 = *(const f32x4*)(rr0 + 32);
  f32x4 nx3 = *(const f32x4*)(rr0 + 36);

  unsigned int* hrow = hbuf + ((w << 4) + qh) * 32;
  const int swz = qh & 7;

  for (int s = 0; s < 32; ++s) {
    const int p = (s << 3) + w;
    f32x4 r0 = nx0, r1 = nx1, r2 = nx2, r3 = nx3;
    {
      const int pn = (s < 31) ? p + 8 : p;
      const float* rr = rbf + ((nbase + pn) * 256 + q0 + qh) * 64 + (g << 3);
      nx0 = *(const f32x4*)(rr);
      nx1 = *(const f32x4*)(rr + 4);
      nx2 = *(const f32x4*)(rr + 32);
      nx3 = *(const f32x4*)(rr + 36);
    }
    const float* uvp = uv + ((nbase + p) * 256 + q0 + qh) * 3;
    const float su = SU * uvp[0];
    const float sv = SU * uvp[1];
    const float swc = SW * uvp[2];

    const short8 rf0 = mk8(pkbf(r0[0], r0[1]), pkbf(r0[2], r0[3]), pkbf(r1[0], r1[1]), pkbf(r1[2], r1[3]));
    const short8 rf1 = mk8(pkbf(r2[0], r2[1]), pkbf(r2[2], r2[3]), pkbf(r3[0], r3[1]), pkbf(r3[2], r3[3]));

    f32x4 h4[4];
    #pragma unroll
    for (int mt = 0; mt < 4; ++mt) {
      f32x4 c = *(const f32x4*)(b1 + (mt << 4) + (g << 2));
      short8 a0 = *(const short8*)(wfrag + (((mt << 1) + 0) * 64 + l) * 4);
      short8 a1 = *(const short8*)(wfrag + (((mt << 1) + 1) * 64 + l) * 4);
      c = MFMA16(a0, rf0, c);
      c = MFMA16(a1, rf1, c);
      h4[mt] = c;
    }
    #pragma unroll
    for (int mt = 0; mt < 4; ++mt) {
      const float e0 = fmaxf(h4[mt][0], 0.f);
      const float e1 = fmaxf(h4[mt][1], 0.f);
      const float e2 = fmaxf(h4[mt][2], 0.f);
      const float e3 = fmaxf(h4[mt][3], 0.f);
      const int base = ((((mt << 1) + (g >> 1)) ^ swz) << 2) + ((g & 1) << 1);
      hrow[base]     = pkbf(e0, e1);
      hrow[base + 1] = pkbf(e2, e3);
    }
    const short8 hb0 = *(const short8*)(hrow + (((0 + g) ^ swz) << 2));
    const short8 hb1 = *(const short8*)(hrow + (((4 + g) ^ swz) << 2));

    const float* i1p = inp1 + (nbase + p) * 192 + (g << 2);
    const float* i2p = inp2 + (nbase + p) * 192 + (g << 2);

    #pragma unroll
    for (int mt2 = 0; mt2 < 4; ++mt2) {
      f32x4 c = *(const f32x4*)(b2 + (mt2 << 4) + (g << 2));
      short8 wa0 = *(const short8*)(wfrag + ((8 + (mt2 << 1) + 0) * 64 + l) * 4);
      short8 wa1 = *(const short8*)(wfrag + ((8 + (mt2 << 1) + 1) * 64 + l) * 4);
      c = MFMA16(wa0, hb0, c);
      c = MFMA16(wa1, hb1, c);

      const int fo = mt2 << 4;
      const f32x4 A0 = *(const f32x4*)(i1p + fo);
      const f32x4 A1 = *(const f32x4*)(i1p + fo + 64);
      const f32x4 A2 = *(const f32x4*)(i1p + fo + 128);
      const f32x4 B0 = *(const f32x4*)(i2p + fo);
      const f32x4 B1 = *(const f32x4*)(i2p + fo + 64);
      const f32x4 B2 = *(const f32x4*)(i2p + fo + 128);
      const f32x4 a02p = A0 + A2, a02m = A0 - A2;
      const f32x4 b02p = B0 + B2, b02m = B0 - B2;

      #pragma unroll
      for (int v = 0; v < 4; ++v) {
        const float R = c[v];
        const float pua1 = su * A1[v], pvb1 = sv * B1[v];
        const float pub1 = su * B1[v], pva1 = sv * A1[v];
        const float g10 = pua1 - swc * A0[v] + pvb1;
        const float g11 = su * a02p[v] - sv * b02m[v];
        const float g12 = swc * A2[v] + pua1 - pvb1;
        const float g20 = pub1 - swc * B0[v] - pva1;
        const float g21 = sv * a02m[v] + su * b02p[v];
        const float g22 = swc * B2[v] + pub1 + pva1;
        accT[mt2][v][0] += R * g10;
        accT[mt2][v][1] += R * g11;
        accT[mt2][v][2] += R * g12;
        accT[mt2][v][3] += R * g20;
        accT[mt2][v][4] += R * g21;
        accT[mt2][v][5] += R * g22;
      }
    }
  }

  __syncthreads();
  for (int i = tid; i < 16 * 64 * 6; i += 512) accL[i] = 0.f;
  #pragma unroll
  for (int k = 0; k < 8; ++k) {
    const int f = (w << 3) + k;
    wsiT[(f << 6) + l] = Wsi[(l << 6) + f];
  }
  __syncthreads();

  for (int t = 0; t < 8; ++t) {
    if (w == t) {
      #pragma unroll
      for (int mt2 = 0; mt2 < 4; ++mt2)
        #pragma unroll
        for (int v = 0; v < 4; ++v) {
          float* dst = accL + (((qh << 6) + (mt2 << 4) + (g << 2) + v) * 6);
          #pragma unroll
          for (int j = 0; j < 6; ++j) dst[j] += accT[mt2][v][j];
        }
    }
    __syncthreads();
  }

  #pragma unroll
  for (int rep = 0; rep < 2; ++rep) {
    const int qq = w + (rep << 3);
    float* xp = accL + ((qq << 6) + l) * 6;
    const float x0 = xp[0], x1 = xp[1], x2 = xp[2], x3 = xp[3], x4 = xp[4], x5 = xp[5];
    const float nrm = sqrtf(x0*x0 + x1*x1 + x2*x2 + x3*x3 + x4*x4 + x5*x5);
    const float sc = 1.f / (nrm + 1e-9f);
    xp[0] = x0 * sc; xp[1] = x1 * sc; xp[2] = x2 * sc;
    xp[3] = x3 * sc; xp[4] = x4 * sc; xp[5] = x5 * sc;
  }
  __syncthreads();

  const float bb = biasb[0];
  #pragma unroll
  for (int rep = 0; rep < 2; ++rep) {
    const int qq = w + (rep << 3);
    const float* arow = accL + (qq << 6) * 6;
    float pj0 = 0, pj1 = 0, pj2 = 0, pj3 = 0, pj4 = 0, pj5 = 0;
    for (int f = 0; f < 64; ++f) {
      const float wv = wsiT[(f << 6) + l];
      const float* ap = arow + f * 6;
      pj0 += ap[0] * wv; pj1 += ap[1] * wv; pj2 += ap[2] * wv;
      pj3 += ap[3] * wv; pj4 += ap[4] * wv; pj5 += ap[5] * wv;
    }
    const float s2 = pj0*pj0 + pj1*pj1 + pj2*pj2 + pj3*pj3 + pj4*pj4 + pj5*pj5;
    const float nl = fmaxf(sqrtf(s2) + bb, 0.f);
    const int q = q0 + qq;
    float* o1 = out + (size_t)((n * 256 + q) * 3) * 64 + l;
    float* o2 = o1 + 786432;
    o1[0]   = pj0 * nl;
    o1[64]  = pj1 * nl;
    o1[128] = pj2 * nl;
    o2[0]   = pj3 * nl;
    o2[64]  = pj4 * nl;
    o2[128] = pj5 * nl;
  }
}

extern "C" void kernel_launch(void* const* d_in, const int* in_sizes, int n_in,
                              void* d_out, int out_size, void* d_ws, size_t ws_size,
                              hipStream_t stream) {
  (void)in_sizes; (void)n_in; (void)out_size;
  const size_t ws_needed = (size_t)512 * 6144 * sizeof(float);   // 12.58 MB
  if (ws_size >= ws_needed) {
    tfield_partial<<<dim3(512), dim3(256), 0, stream>>>(
        (const float*)d_in[0], (const float*)d_in[1],
        (const float*)d_in[2], (const float*)d_in[3],
        (const float*)d_in[6], (const float*)d_in[7],
        (const float*)d_in[8], (const float*)d_in[9],
        (float*)d_ws);
    tfield_finish<<<dim3(256), dim3(512), 0, stream>>>(
        (const float*)d_ws, (const float*)d_in[10],
        (const float*)d_in[11], (float*)d_out);
  } else {
    tfield_kernel<<<dim3(256), dim3(512), 0, stream>>>(
        (const float*)d_in[0], (const float*)d_in[1],
        (const float*)d_in[2], (const float*)d_in[3],
        (const float*)d_in[6], (const float*)d_in[7],
        (const float*)d_in[8], (const float*)d_in[9],
        (const float*)d_in[10], (const float*)d_in[11],
        (float*)d_out);
  }
}